// Round 1
// baseline (5237.822 us; speedup 1.0000x reference)
//
#include <hip/hip_runtime.h>

#define B_ 256
#define L_ 50
#define D_ 128
#define T_ 4
#define NH 8
#define NV 4
#define TB_ (T_*B_)
#define SLP 132          // padded LDS row stride (floats): 528B, 16B-aligned, 4-way conflict max
#define EPSF 1e-5f

__device__ __forceinline__ float waveSum(float v) {
    #pragma unroll
    for (int o = 32; o > 0; o >>= 1) v += __shfl_down(v, o, 64);
    return v;
}

// element offset of scale i inside y buffer: 1024*8*sum_{i'<i}(50-i')
__device__ __forceinline__ size_t yoff(int i) {
    return (size_t)8192 * (size_t)(50 * i - (i * (i - 1)) / 2);
}

// K1: embedding gather + LayerNorm + LIF(T=4) -> s [T,B,L,D] fp32, smean [B,L,D]
__global__ __launch_bounds__(128) void k1_embed_ln_lif(
        const int* __restrict__ item, const float* __restrict__ tab,
        const float* __restrict__ g, const float* __restrict__ be,
        float* __restrict__ s, float* __restrict__ smean) {
    int bid = blockIdx.x;            // 0..B*L-1
    int b = bid / L_, l = bid % L_;
    int d = threadIdx.x;             // 0..127
    int wid = d >> 6, lane = d & 63;
    __shared__ float red[2];
    int it = item[b * L_ + l];
    float e = tab[(size_t)it * D_ + d];
    float sm_ = waveSum(e);
    if (lane == 0) red[wid] = sm_;
    __syncthreads();
    float mu = (red[0] + red[1]) * (1.f / 128.f);
    __syncthreads();
    float df = e - mu;
    float s2 = waveSum(df * df);
    if (lane == 0) red[wid] = s2;
    __syncthreads();
    float var = (red[0] + red[1]) * (1.f / 128.f);
    float x = df / sqrtf(var + EPSF) * g[d] + be[d];
    float v = 0.f, acc = 0.f;
    size_t base = ((size_t)b * L_ + l) * D_ + d;
    #pragma unroll
    for (int t = 0; t < T_; ++t) {
        v += (x - v) * 0.5f;                 // charge, tau=2
        float sp = (v >= 1.f) ? 1.f : 0.f;   // fire
        v *= (1.f - sp);                     // hard reset
        s[(size_t)t * (B_ * L_ * D_) + base] = sp;
        acc += sp;
    }
    smean[base] = acc * 0.25f;
}

// K2: horizontal multi-scale conv. block = (tb, i); y[i][tb][h][j]
__global__ __launch_bounds__(256) void k2_convh(
        const float* __restrict__ s, const float* __restrict__ w, float* __restrict__ y) {
    __shared__ float sl[L_ * SLP];
    int tb = blockIdx.x, i = blockIdx.y, k = i + 1, J = L_ - k + 1;
    int tid = threadIdx.x;
    const float* srow = s + (size_t)tb * (L_ * D_);
    for (int idx = tid; idx < L_ * D_; idx += 256)
        sl[(idx >> 7) * SLP + (idx & 127)] = srow[idx];
    __syncthreads();
    int h = tid >> 5, j0 = tid & 31;
    if (j0 >= J) return;
    const float* wp = w + (size_t)(i * NH + h) * (L_ * D_);
    size_t yb = yoff(i) + ((size_t)tb * NH + h) * J;
    float acc0 = 0.f;
    if (j0 + 32 < J) {
        float acc1 = 0.f;
        for (int dk = 0; dk < k; ++dk) {
            const float4* wr = (const float4*)(wp + dk * D_);
            const float4* a0 = (const float4*)(sl + (j0 + dk) * SLP);
            const float4* a1 = (const float4*)(sl + (j0 + 32 + dk) * SLP);
            #pragma unroll 8
            for (int q = 0; q < 32; ++q) {
                float4 wv = wr[q], x0 = a0[q], x1 = a1[q];
                acc0 += x0.x * wv.x + x0.y * wv.y + x0.z * wv.z + x0.w * wv.w;
                acc1 += x1.x * wv.x + x1.y * wv.y + x1.z * wv.z + x1.w * wv.w;
            }
        }
        y[yb + j0] = acc0;
        y[yb + j0 + 32] = acc1;
    } else {
        for (int dk = 0; dk < k; ++dk) {
            const float4* wr = (const float4*)(wp + dk * D_);
            const float4* a0 = (const float4*)(sl + (j0 + dk) * SLP);
            #pragma unroll 8
            for (int q = 0; q < 32; ++q) {
                float4 wv = wr[q], x0 = a0[q];
                acc0 += x0.x * wv.x + x0.y * wv.y + x0.z * wv.z + x0.w * wv.w;
            }
        }
        y[yb + j0] = acc0;
    }
}

// K3: BN stats per (i,h): mean + gamma/sqrt(var+eps). Deterministic block reduce.
__global__ __launch_bounds__(256) void k3_stats(
        const float* __restrict__ y, const float* __restrict__ bng,
        float* __restrict__ statm, float* __restrict__ stats_) {
    int ih = blockIdx.x;             // 0..399
    int i = ih >> 3, h = ih & 7;
    int k = i + 1, J = L_ - k + 1;
    size_t yb = yoff(i);
    int tid = threadIdx.x;
    int grp = tid >> 5, sub = tid & 31;
    float sm_ = 0.f, ss = 0.f;
    for (int tb = grp; tb < TB_; tb += 8) {
        const float* row = y + yb + ((size_t)tb * NH + h) * J;
        for (int j = sub; j < J; j += 32) {
            float v = row[j];
            sm_ += v; ss += v * v;
        }
    }
    __shared__ float r1[4], r2[4];
    float a = waveSum(sm_), bq = waveSum(ss);
    int wid = tid >> 6, lane = tid & 63;
    if (lane == 0) { r1[wid] = a; r2[wid] = bq; }
    __syncthreads();
    if (tid == 0) {
        float S = r1[0] + r1[1] + r1[2] + r1[3];
        float Q = r2[0] + r2[1] + r2[2] + r2[3];
        float cnt = (float)(TB_) * (float)J;
        float m = S / cnt;
        float var = Q / cnt - m * m;
        if (var < 0.f) var = 0.f;
        statm[ih] = m;
        stats_[ih] = bng[ih] / sqrtf(var + EPSF);
    }
}

// K4: BN + LIF over t + max-pool over j (binary OR) -> poolsum [B,400]
__global__ __launch_bounds__(512) void k4_bn_lif_pool(
        const float* __restrict__ y, const float* __restrict__ statm,
        const float* __restrict__ stats_, const float* __restrict__ bnb,
        float* __restrict__ ps) {
    int b = blockIdx.x, i = blockIdx.y, k = i + 1, J = L_ - k + 1;
    int h = threadIdx.x >> 6, lane = threadIdx.x & 63;
    int ih = i * NH + h;
    float m = statm[ih], sc = stats_[ih], bb = bnb[ih];
    size_t yb = yoff(i);
    bool valid = lane < J;
    float v = 0.f; int cnt = 0;
    #pragma unroll
    for (int t = 0; t < T_; ++t) {
        int tb = t * B_ + b;
        float yn;
        if (valid) {
            float raw = y[yb + ((size_t)tb * NH + h) * J + lane];
            yn = (raw - m) * sc + bb;
        } else yn = -1e30f;
        v += (yn - v) * 0.5f;
        bool sp = (v >= 1.f);
        if (sp) v = 0.f;
        if (__any(sp)) cnt++;
    }
    if (lane == 0) ps[(size_t)b * 400 + ih] = (float)cnt;
}

// K5: per-b fused heads: out = fc_h(poolmean) + fc_v(vertical conv of smean)
__global__ __launch_bounds__(128) void k5_final(
        const float* __restrict__ smean, const float* __restrict__ ps,
        const float* __restrict__ convv, const float* __restrict__ fchw,
        const float* __restrict__ fchb, const float* __restrict__ fcvw,
        const float* __restrict__ fcvb, float* __restrict__ out) {
    __shared__ float sm_l[L_ * D_];   // 25.6KB
    __shared__ float vm[NV * D_];
    __shared__ float ps_l[400];
    int b = blockIdx.x, tid = threadIdx.x;
    for (int idx = tid; idx < L_ * D_; idx += 128) sm_l[idx] = smean[(size_t)b * (L_ * D_) + idx];
    for (int idx = tid; idx < 400; idx += 128) ps_l[idx] = ps[(size_t)b * 400 + idx];
    __syncthreads();
    int d = tid;
    #pragma unroll
    for (int c = 0; c < NV; ++c) {
        float a = 0.f;
        for (int l = 0; l < L_; ++l) a += convv[c * L_ + l] * sm_l[l * D_ + d];
        vm[c * D_ + d] = a;
    }
    __syncthreads();
    float acc = fchb[d] + fcvb[d];
    float ah = 0.f;
    for (int ih = 0; ih < 400; ++ih) ah += ps_l[ih] * fchw[d * 400 + ih];
    acc += ah * 0.25f;
    float av = 0.f;
    for (int cd = 0; cd < NV * D_; ++cd) av += vm[cd] * fcvw[d * (NV * D_) + cd];
    acc += av;
    out[(size_t)b * D_ + d] = acc;
}

extern "C" void kernel_launch(void* const* d_in, const int* in_sizes, int n_in,
                              void* d_out, int out_size, void* d_ws, size_t ws_size,
                              hipStream_t stream) {
    const int*   item  = (const int*)d_in[0];
    const float* tab   = (const float*)d_in[1];
    const float* lng   = (const float*)d_in[2];
    const float* lnb   = (const float*)d_in[3];
    const float* convv = (const float*)d_in[4];
    const float* convh = (const float*)d_in[5];
    const float* bng   = (const float*)d_in[6];
    const float* bnb   = (const float*)d_in[7];
    const float* fchw  = (const float*)d_in[8];
    const float* fchb  = (const float*)d_in[9];
    const float* fcvw  = (const float*)d_in[10];
    const float* fcvb  = (const float*)d_in[11];
    float* out = (float*)d_out;

    char* ws = (char*)d_ws;
    // layout (bytes): s 26,214,400 | smean 6,553,600 | y 41,779,200 | statm/stats 3,200 | ps 409,600
    float* s      = (float*)(ws);
    float* smean  = (float*)(ws + 26214400LL);
    float* y      = (float*)(ws + 32768000LL);
    float* statm  = (float*)(ws + 74547200LL);
    float* stats_ = (float*)(ws + 74548800LL);
    float* ps     = (float*)(ws + 74550400LL);
    // total required ~74.96 MB of d_ws

    k1_embed_ln_lif<<<B_ * L_, 128, 0, stream>>>(item, tab, lng, lnb, s, smean);
    k2_convh<<<dim3(TB_, L_), 256, 0, stream>>>(s, convh, y);
    k3_stats<<<400, 256, 0, stream>>>(y, bng, statm, stats_);
    k4_bn_lif_pool<<<dim3(B_, L_), 512, 0, stream>>>(y, statm, stats_, bnb, ps);
    k5_final<<<B_, 128, 0, stream>>>(smean, ps, convv, fchw, fchb, fcvw, fcvb, out);
}

// Round 2
// 4756.202 us; speedup vs baseline: 1.1013x; 1.1013x over previous
//
#include <hip/hip_runtime.h>

#define B_ 256
#define L_ 50
#define D_ 128
#define T_ 4
#define NH 8
#define NV 4
#define TB_ (T_*B_)
#define SLP 132          // padded LDS row stride (floats) = 33 float4s (odd) -> conflict-free-ish
#define EPSF 1e-5f

__device__ __forceinline__ float waveSum(float v) {
    #pragma unroll
    for (int o = 32; o > 0; o >>= 1) v += __shfl_down(v, o, 64);
    return v;
}

// element offset of scale i inside y buffer: 1024*8*sum_{i'<i}(50-i')
__device__ __forceinline__ size_t yoff(int i) {
    return (size_t)8192 * (size_t)(50 * i - (i * (i - 1)) / 2);
}

// K1: embedding gather + LayerNorm + LIF(T=4) -> s [T,B,L,D] fp32, smean [B,L,D]
__global__ __launch_bounds__(128) void k1_embed_ln_lif(
        const int* __restrict__ item, const float* __restrict__ tab,
        const float* __restrict__ g, const float* __restrict__ be,
        float* __restrict__ s, float* __restrict__ smean) {
    int bid = blockIdx.x;            // 0..B*L-1
    int b = bid / L_, l = bid % L_;
    int d = threadIdx.x;             // 0..127
    int wid = d >> 6, lane = d & 63;
    __shared__ float red[2];
    int it = item[b * L_ + l];
    float e = tab[(size_t)it * D_ + d];
    float sm_ = waveSum(e);
    if (lane == 0) red[wid] = sm_;
    __syncthreads();
    float mu = (red[0] + red[1]) * (1.f / 128.f);
    __syncthreads();
    float df = e - mu;
    float s2 = waveSum(df * df);
    if (lane == 0) red[wid] = s2;
    __syncthreads();
    float var = (red[0] + red[1]) * (1.f / 128.f);
    float x = df / sqrtf(var + EPSF) * g[d] + be[d];
    float v = 0.f, acc = 0.f;
    size_t base = ((size_t)b * L_ + l) * D_ + d;
    #pragma unroll
    for (int t = 0; t < T_; ++t) {
        v += (x - v) * 0.5f;                 // charge, tau=2
        float sp = (v >= 1.f) ? 1.f : 0.f;   // fire
        v *= (1.f - sp);                     // hard reset
        s[(size_t)t * (B_ * L_ * D_) + base] = sp;
        acc += sp;
    }
    smean[base] = acc * 0.25f;
}

// K2: horizontal multi-scale conv. block=(tb, i), 256 threads.
// Thread layout: jl = tid&31 (output column), slot = tid>>5:
//   hg = slot&1 (4-h group), dp = slot>>1 (dk residue mod 4).
// Each thread: acc[4] (h-channels) x up to 2 j-columns; dk-partials reduced via LDS.
__global__ __launch_bounds__(256) void k2_convh(
        const float* __restrict__ s, const float* __restrict__ w, float* __restrict__ y) {
    __shared__ float sl[L_ * SLP];       // 26400 B
    __shared__ float red[4][8][64];      // 8192 B  [dp][h][j]
    int tb = blockIdx.x, i = blockIdx.y;
    int k = i + 1, J = L_ - k + 1;       // J = 50 - i
    int tid = threadIdx.x;

    // stage s[tb] into LDS (padded rows)
    const float* srow = s + (size_t)tb * (L_ * D_);
    for (int idx = tid; idx < L_ * D_; idx += 256)
        sl[(idx >> 7) * SLP + (idx & 127)] = srow[idx];
    __syncthreads();

    int jl = tid & 31, slot = tid >> 5;
    int hg = slot & 1, dp = slot >> 1;
    bool two = (J > 32);

    const float4* sl4 = (const float4*)sl;
    // weight row (hh, dk): wb4 + hh*1600 + dk*32 + q
    const float4* wb4 = (const float4*)w + (size_t)(i * NH + hg * 4) * (L_ * 32);

    float acc0[4] = {0.f, 0.f, 0.f, 0.f};
    float acc1[4] = {0.f, 0.f, 0.f, 0.f};

    if (jl < J) {
        for (int dk = dp; dk < k; dk += 4) {
            const float4* s0 = sl4 + (jl + dk) * 33;
            int r2 = jl + 32 + dk; if (r2 > 49) r2 = 49;   // clamp (lanes whose acc1 is unused)
            const float4* s1 = sl4 + r2 * 33;
            const float4* w0 = wb4 + dk * 32;
            if (two) {
                #pragma unroll 4
                for (int q = 0; q < 32; ++q) {
                    float4 a = s0[q], b = s1[q];
                    #pragma unroll
                    for (int hh = 0; hh < 4; ++hh) {
                        float4 wv = w0[hh * 1600 + q];
                        acc0[hh] += a.x * wv.x + a.y * wv.y + a.z * wv.z + a.w * wv.w;
                        acc1[hh] += b.x * wv.x + b.y * wv.y + b.z * wv.z + b.w * wv.w;
                    }
                }
            } else {
                #pragma unroll 4
                for (int q = 0; q < 32; ++q) {
                    float4 a = s0[q];
                    #pragma unroll
                    for (int hh = 0; hh < 4; ++hh) {
                        float4 wv = w0[hh * 1600 + q];
                        acc0[hh] += a.x * wv.x + a.y * wv.y + a.z * wv.z + a.w * wv.w;
                    }
                }
            }
        }
    }

    // write dk-partials
    if (jl < J) {
        #pragma unroll
        for (int hh = 0; hh < 4; ++hh) red[dp][hg * 4 + hh][jl] = acc0[hh];
        if (two && jl + 32 < J) {
            #pragma unroll
            for (int hh = 0; hh < 4; ++hh) red[dp][hg * 4 + hh][jl + 32] = acc1[hh];
        }
    }
    __syncthreads();

    // reduce over dp and store y[i][tb][h][j]
    size_t yb = yoff(i) + (size_t)tb * NH * J;
    for (int e = tid; e < 8 * 64; e += 256) {
        int j = e & 63, h = e >> 6;
        if (j < J) {
            float sum = red[0][h][j] + red[1][h][j] + red[2][h][j] + red[3][h][j];
            y[yb + (size_t)h * J + j] = sum;
        }
    }
}

// K3: BN stats per (i,h): mean + gamma/sqrt(var+eps). Deterministic block reduce.
__global__ __launch_bounds__(256) void k3_stats(
        const float* __restrict__ y, const float* __restrict__ bng,
        float* __restrict__ statm, float* __restrict__ stats_) {
    int ih = blockIdx.x;             // 0..399
    int i = ih >> 3, h = ih & 7;
    int k = i + 1, J = L_ - k + 1;
    size_t yb = yoff(i);
    int tid = threadIdx.x;
    int grp = tid >> 5, sub = tid & 31;
    float sm_ = 0.f, ss = 0.f;
    for (int tb = grp; tb < TB_; tb += 8) {
        const float* row = y + yb + ((size_t)tb * NH + h) * J;
        for (int j = sub; j < J; j += 32) {
            float v = row[j];
            sm_ += v; ss += v * v;
        }
    }
    __shared__ float r1[4], r2[4];
    float a = waveSum(sm_), bq = waveSum(ss);
    int wid = tid >> 6, lane = tid & 63;
    if (lane == 0) { r1[wid] = a; r2[wid] = bq; }
    __syncthreads();
    if (tid == 0) {
        float S = r1[0] + r1[1] + r1[2] + r1[3];
        float Q = r2[0] + r2[1] + r2[2] + r2[3];
        float cnt = (float)(TB_) * (float)J;
        float m = S / cnt;
        float var = Q / cnt - m * m;
        if (var < 0.f) var = 0.f;
        statm[ih] = m;
        stats_[ih] = bng[ih] / sqrtf(var + EPSF);
    }
}

// K4: BN + LIF over t + max-pool over j (binary OR) -> poolsum [B,400]
__global__ __launch_bounds__(512) void k4_bn_lif_pool(
        const float* __restrict__ y, const float* __restrict__ statm,
        const float* __restrict__ stats_, const float* __restrict__ bnb,
        float* __restrict__ ps) {
    int b = blockIdx.x, i = blockIdx.y, k = i + 1, J = L_ - k + 1;
    int h = threadIdx.x >> 6, lane = threadIdx.x & 63;
    int ih = i * NH + h;
    float m = statm[ih], sc = stats_[ih], bb = bnb[ih];
    size_t yb = yoff(i);
    bool valid = lane < J;
    float v = 0.f; int cnt = 0;
    #pragma unroll
    for (int t = 0; t < T_; ++t) {
        int tb = t * B_ + b;
        float yn;
        if (valid) {
            float raw = y[yb + ((size_t)tb * NH + h) * J + lane];
            yn = (raw - m) * sc + bb;
        } else yn = -1e30f;
        v += (yn - v) * 0.5f;
        bool sp = (v >= 1.f);
        if (sp) v = 0.f;
        if (__any(sp)) cnt++;
    }
    if (lane == 0) ps[(size_t)b * 400 + ih] = (float)cnt;
}

// K5: per-b fused heads: out = fc_h(poolmean) + fc_v(vertical conv of smean)
__global__ __launch_bounds__(128) void k5_final(
        const float* __restrict__ smean, const float* __restrict__ ps,
        const float* __restrict__ convv, const float* __restrict__ fchw,
        const float* __restrict__ fchb, const float* __restrict__ fcvw,
        const float* __restrict__ fcvb, float* __restrict__ out) {
    __shared__ float sm_l[L_ * D_];   // 25.6KB
    __shared__ float vm[NV * D_];
    __shared__ float ps_l[400];
    int b = blockIdx.x, tid = threadIdx.x;
    for (int idx = tid; idx < L_ * D_; idx += 128) sm_l[idx] = smean[(size_t)b * (L_ * D_) + idx];
    for (int idx = tid; idx < 400; idx += 128) ps_l[idx] = ps[(size_t)b * 400 + idx];
    __syncthreads();
    int d = tid;
    #pragma unroll
    for (int c = 0; c < NV; ++c) {
        float a = 0.f;
        for (int l = 0; l < L_; ++l) a += convv[c * L_ + l] * sm_l[l * D_ + d];
        vm[c * D_ + d] = a;
    }
    __syncthreads();
    float acc = fchb[d] + fcvb[d];
    float ah = 0.f;
    for (int ih = 0; ih < 400; ++ih) ah += ps_l[ih] * fchw[d * 400 + ih];
    acc += ah * 0.25f;
    float av = 0.f;
    for (int cd = 0; cd < NV * D_; ++cd) av += vm[cd] * fcvw[d * (NV * D_) + cd];
    acc += av;
    out[(size_t)b * D_ + d] = acc;
}

extern "C" void kernel_launch(void* const* d_in, const int* in_sizes, int n_in,
                              void* d_out, int out_size, void* d_ws, size_t ws_size,
                              hipStream_t stream) {
    const int*   item  = (const int*)d_in[0];
    const float* tab   = (const float*)d_in[1];
    const float* lng   = (const float*)d_in[2];
    const float* lnb   = (const float*)d_in[3];
    const float* convv = (const float*)d_in[4];
    const float* convh = (const float*)d_in[5];
    const float* bng   = (const float*)d_in[6];
    const float* bnb   = (const float*)d_in[7];
    const float* fchw  = (const float*)d_in[8];
    const float* fchb  = (const float*)d_in[9];
    const float* fcvw  = (const float*)d_in[10];
    const float* fcvb  = (const float*)d_in[11];
    float* out = (float*)d_out;

    char* ws = (char*)d_ws;
    // layout (bytes): s 26,214,400 | smean 6,553,600 | y 41,779,200 | statm/stats 3,200 | ps 409,600
    float* s      = (float*)(ws);
    float* smean  = (float*)(ws + 26214400LL);
    float* y      = (float*)(ws + 32768000LL);
    float* statm  = (float*)(ws + 74547200LL);
    float* stats_ = (float*)(ws + 74548800LL);
    float* ps     = (float*)(ws + 74550400LL);
    // total required ~74.96 MB of d_ws

    k1_embed_ln_lif<<<B_ * L_, 128, 0, stream>>>(item, tab, lng, lnb, s, smean);
    k2_convh<<<dim3(TB_, L_), 256, 0, stream>>>(s, convh, y);
    k3_stats<<<400, 256, 0, stream>>>(y, bng, statm, stats_);
    k4_bn_lif_pool<<<dim3(B_, L_), 512, 0, stream>>>(y, statm, stats_, bnb, ps);
    k5_final<<<B_, 128, 0, stream>>>(smean, ps, convv, fchw, fchb, fcvw, fcvb, out);
}

// Round 3
// 485.370 us; speedup vs baseline: 10.7914x; 9.7991x over previous
//
#include <hip/hip_runtime.h>

#define B_ 256
#define L_ 50
#define D_ 128
#define T_ 4
#define NH 8
#define NV 4
#define TB_ (T_*B_)
#define EPSF 1e-5f

typedef _Float16 h8 __attribute__((ext_vector_type(8)));
typedef float f4 __attribute__((ext_vector_type(4)));

__device__ __forceinline__ float waveSum(float v) {
    #pragma unroll
    for (int o = 32; o > 0; o >>= 1) v += __shfl_down(v, o, 64);
    return v;
}

// element offset of scale i inside y buffer: 1024*8*sum_{i'<i}(50-i')
__device__ __forceinline__ size_t yoff(int i) {
    return (size_t)8192 * (size_t)(50 * i - (i * (i - 1)) / 2);
}

// K0: split conv_h_w fp32 -> fp16 (hi | lo*1024), transposed to [i][dk][c=16][d]
__global__ __launch_bounds__(256) void k0_wsplit(
        const float* __restrict__ w, _Float16* __restrict__ whl) {
    int dk = blockIdx.x, i = blockIdx.y;
    int t = threadIdx.x;
    int c = t >> 4, d0 = (t & 15) * 8;
    int h = c & 7;
    const float* src = w + (((size_t)i * NH + h) * L_ + dk) * D_ + d0;
    h8 o;
    #pragma unroll
    for (int e = 0; e < 8; ++e) {
        float wv = src[e];
        _Float16 hi = (_Float16)wv;
        o[e] = (c < 8) ? hi : (_Float16)((wv - (float)hi) * 1024.f);
    }
    *(h8*)(whl + (((size_t)i * L_ + dk) * 16 + c) * D_ + d0) = o;
}

// K1: embedding gather + LayerNorm + LIF(T=4) -> s16 [T,B,L,D] fp16, smean [B,L,D] fp32
__global__ __launch_bounds__(128) void k1_embed_ln_lif(
        const int* __restrict__ item, const float* __restrict__ tab,
        const float* __restrict__ g, const float* __restrict__ be,
        _Float16* __restrict__ s16, float* __restrict__ smean) {
    int bid = blockIdx.x;            // 0..B*L-1
    int b = bid / L_, l = bid % L_;
    int d = threadIdx.x;             // 0..127
    int wid = d >> 6, lane = d & 63;
    __shared__ float red[2];
    int it = item[b * L_ + l];
    float e = tab[(size_t)it * D_ + d];
    float sm_ = waveSum(e);
    if (lane == 0) red[wid] = sm_;
    __syncthreads();
    float mu = (red[0] + red[1]) * (1.f / 128.f);
    __syncthreads();
    float df = e - mu;
    float s2 = waveSum(df * df);
    if (lane == 0) red[wid] = s2;
    __syncthreads();
    float var = (red[0] + red[1]) * (1.f / 128.f);
    float x = df / sqrtf(var + EPSF) * g[d] + be[d];
    float v = 0.f, acc = 0.f;
    size_t base = ((size_t)b * L_ + l) * D_ + d;
    #pragma unroll
    for (int t = 0; t < T_; ++t) {
        v += (x - v) * 0.5f;                 // charge, tau=2
        float sp = (v >= 1.f) ? 1.f : 0.f;   // fire
        v *= (1.f - sp);                     // hard reset
        s16[(size_t)t * (B_ * L_ * D_) + base] = (_Float16)sp;
        acc += sp;
    }
    smean[base] = acc * 0.25f;
}

// ---- K2: MFMA implicit-im2col conv ----
// block=(tbq, i), 256 threads = 4 waves, wave = tb_local.
// LDS: A = 4 tb x 50 rows x 256B (swizzled slots), B = 2 x 4KB double buffer.
#define LDSA(tbL, l, slot)  ((tbL) * 12800 + (l) * 256 + (((slot) ^ (l)) & 15) * 16)
#define LDSB(buf, c, slot)  (51200 + (buf) * 4096 + (c) * 256 + (((slot) ^ (c)) & 15) * 16)

__device__ __forceinline__ void epiStore(f4 a, int mt, int J, int g, bool hiLane,
                                         float* __restrict__ y, size_t ybase) {
    #pragma unroll
    for (int r = 0; r < 4; ++r) {
        float lo = __shfl_xor(a[r], 8, 64);
        int j = mt * 16 + g * 4 + r;
        if (hiLane && j < J) y[ybase + j] = a[r] + lo * (1.f / 1024.f);
    }
}

__global__ __launch_bounds__(256) void k2_convh_mfma(
        const _Float16* __restrict__ s16, const _Float16* __restrict__ whl,
        float* __restrict__ y) {
    __shared__ __align__(16) char lds[51200 + 8192];
    int tbq = blockIdx.x, i = blockIdx.y;
    int k = i + 1, J = L_ - i;
    int Mt = (J + 15) >> 4;
    int tid = threadIdx.x;
    int wave = tid >> 6, lane = tid & 63;

    // stage A: 4 tb x 800 16B-chunks
    for (int c = tid; c < 3200; c += 256) {
        int tbL = c / 800, rem = c - tbL * 800;
        int l = rem >> 4, sl = rem & 15;
        float4 v = *(const float4*)(s16 + (size_t)(tbq * 4 + tbL) * (L_ * D_) + l * D_ + sl * 8);
        *(float4*)(lds + LDSA(tbL, l, sl)) = v;
    }
    // stage B[dk=0]
    int bc = tid >> 4, bs = tid & 15;
    {
        float4 v = *(const float4*)(whl + ((size_t)i * L_ * 16 + bc) * D_ + bs * 8);
        *(float4*)(lds + LDSB(0, bc, bs)) = v;
    }
    __syncthreads();

    f4 acc0 = {0.f, 0.f, 0.f, 0.f};
    f4 acc1 = acc0, acc2 = acc0, acc3 = acc0;
    int c_ = lane & 15, g = lane >> 4;
    const char* ldsA = lds + wave * 12800;

    for (int dk = 0; dk < k; ++dk) {
        float4 nxt;
        bool more = (dk + 1 < k);
        if (more)
            nxt = *(const float4*)(whl + (((size_t)i * L_ + (dk + 1)) * 16 + bc) * D_ + bs * 8);

        const char* ldsB = lds + 51200 + (dk & 1) * 4096 + c_ * 256;
        int swb = c_ & 15;
        h8 b0 = *(const h8*)(ldsB + (((0  + g) ^ swb) & 15) * 16);
        h8 b1 = *(const h8*)(ldsB + (((4  + g) ^ swb) & 15) * 16);
        h8 b2 = *(const h8*)(ldsB + (((8  + g) ^ swb) & 15) * 16);
        h8 b3 = *(const h8*)(ldsB + (((12 + g) ^ swb) & 15) * 16);

        #define MT_STEP(ACC, MT)                                                        \
        {                                                                               \
            int l = MT * 16 + c_ + dk; if (l > 49) l = 49;                              \
            const char* ar = ldsA + l * 256; int sw = l & 15;                           \
            h8 a0 = *(const h8*)(ar + (((0  + g) ^ sw) & 15) * 16);                     \
            h8 a1 = *(const h8*)(ar + (((4  + g) ^ sw) & 15) * 16);                     \
            h8 a2 = *(const h8*)(ar + (((8  + g) ^ sw) & 15) * 16);                     \
            h8 a3 = *(const h8*)(ar + (((12 + g) ^ sw) & 15) * 16);                     \
            ACC = __builtin_amdgcn_mfma_f32_16x16x32_f16(a0, b0, ACC, 0, 0, 0);         \
            ACC = __builtin_amdgcn_mfma_f32_16x16x32_f16(a1, b1, ACC, 0, 0, 0);         \
            ACC = __builtin_amdgcn_mfma_f32_16x16x32_f16(a2, b2, ACC, 0, 0, 0);         \
            ACC = __builtin_amdgcn_mfma_f32_16x16x32_f16(a3, b3, ACC, 0, 0, 0);         \
        }
        MT_STEP(acc0, 0)
        if (Mt > 1) MT_STEP(acc1, 1)
        if (Mt > 2) MT_STEP(acc2, 2)
        if (Mt > 3) MT_STEP(acc3, 3)
        #undef MT_STEP

        if (more)
            *(float4*)(lds + LDSB((dk + 1) & 1, bc, bs)) = nxt;
        __syncthreads();
    }

    // epilogue: combine hi (cols 0-7) + lo (cols 8-15)/1024, store
    int tb = tbq * 4 + wave;
    int hh = c_ & 7;
    bool hiLane = (c_ < 8);
    size_t ybase = yoff(i) + ((size_t)tb * NH + hh) * J;
    epiStore(acc0, 0, J, g, hiLane, y, ybase);
    if (Mt > 1) epiStore(acc1, 1, J, g, hiLane, y, ybase);
    if (Mt > 2) epiStore(acc2, 2, J, g, hiLane, y, ybase);
    if (Mt > 3) epiStore(acc3, 3, J, g, hiLane, y, ybase);
}

// K3: BN stats per (i,h): mean + gamma/sqrt(var+eps). Deterministic block reduce.
__global__ __launch_bounds__(256) void k3_stats(
        const float* __restrict__ y, const float* __restrict__ bng,
        float* __restrict__ statm, float* __restrict__ stats_) {
    int ih = blockIdx.x;             // 0..399
    int i = ih >> 3, h = ih & 7;
    int J = L_ - i;
    size_t yb = yoff(i);
    int tid = threadIdx.x;
    int grp = tid >> 5, sub = tid & 31;
    float sm_ = 0.f, ss = 0.f;
    for (int tb = grp; tb < TB_; tb += 8) {
        const float* row = y + yb + ((size_t)tb * NH + h) * J;
        for (int j = sub; j < J; j += 32) {
            float v = row[j];
            sm_ += v; ss += v * v;
        }
    }
    __shared__ float r1[4], r2[4];
    float a = waveSum(sm_), bq = waveSum(ss);
    int wid = tid >> 6, lane = tid & 63;
    if (lane == 0) { r1[wid] = a; r2[wid] = bq; }
    __syncthreads();
    if (tid == 0) {
        float S = r1[0] + r1[1] + r1[2] + r1[3];
        float Q = r2[0] + r2[1] + r2[2] + r2[3];
        float cnt = (float)(TB_) * (float)J;
        float m = S / cnt;
        float var = Q / cnt - m * m;
        if (var < 0.f) var = 0.f;
        statm[ih] = m;
        stats_[ih] = bng[ih] / sqrtf(var + EPSF);
    }
}

// K4: BN + LIF over t + max-pool over j (binary OR) -> poolsum [B,400]
__global__ __launch_bounds__(512) void k4_bn_lif_pool(
        const float* __restrict__ y, const float* __restrict__ statm,
        const float* __restrict__ stats_, const float* __restrict__ bnb,
        float* __restrict__ ps) {
    int b = blockIdx.x, i = blockIdx.y, J = L_ - i;
    int h = threadIdx.x >> 6, lane = threadIdx.x & 63;
    int ih = i * NH + h;
    float m = statm[ih], sc = stats_[ih], bb = bnb[ih];
    size_t yb = yoff(i);
    bool valid = lane < J;
    float v = 0.f; int cnt = 0;
    #pragma unroll
    for (int t = 0; t < T_; ++t) {
        int tb = t * B_ + b;
        float yn;
        if (valid) {
            float raw = y[yb + ((size_t)tb * NH + h) * J + lane];
            yn = (raw - m) * sc + bb;
        } else yn = -1e30f;
        v += (yn - v) * 0.5f;
        bool sp = (v >= 1.f);
        if (sp) v = 0.f;
        if (__any(sp)) cnt++;
    }
    if (lane == 0) ps[(size_t)b * 400 + ih] = (float)cnt;
}

// K5: per-b fused heads: out = fc_h(poolmean) + fc_v(vertical conv of smean)
__global__ __launch_bounds__(128) void k5_final(
        const float* __restrict__ smean, const float* __restrict__ ps,
        const float* __restrict__ convv, const float* __restrict__ fchw,
        const float* __restrict__ fchb, const float* __restrict__ fcvw,
        const float* __restrict__ fcvb, float* __restrict__ out) {
    __shared__ float sm_l[L_ * D_];   // 25.6KB
    __shared__ float vm[NV * D_];
    __shared__ float ps_l[400];
    int b = blockIdx.x, tid = threadIdx.x;
    for (int idx = tid; idx < L_ * D_; idx += 128) sm_l[idx] = smean[(size_t)b * (L_ * D_) + idx];
    for (int idx = tid; idx < 400; idx += 128) ps_l[idx] = ps[(size_t)b * 400 + idx];
    __syncthreads();
    int d = tid;
    #pragma unroll
    for (int c = 0; c < NV; ++c) {
        float a = 0.f;
        for (int l = 0; l < L_; ++l) a += convv[c * L_ + l] * sm_l[l * D_ + d];
        vm[c * D_ + d] = a;
    }
    __syncthreads();
    float acc = fchb[d] + fcvb[d];
    float ah = 0.f;
    for (int ih = 0; ih < 400; ++ih) ah += ps_l[ih] * fchw[d * 400 + ih];
    acc += ah * 0.25f;
    float av = 0.f;
    for (int cd = 0; cd < NV * D_; ++cd) av += vm[cd] * fcvw[d * (NV * D_) + cd];
    acc += av;
    out[(size_t)b * D_ + d] = acc;
}

extern "C" void kernel_launch(void* const* d_in, const int* in_sizes, int n_in,
                              void* d_out, int out_size, void* d_ws, size_t ws_size,
                              hipStream_t stream) {
    const int*   item  = (const int*)d_in[0];
    const float* tab   = (const float*)d_in[1];
    const float* lng   = (const float*)d_in[2];
    const float* lnb   = (const float*)d_in[3];
    const float* convv = (const float*)d_in[4];
    const float* convh = (const float*)d_in[5];
    const float* bng   = (const float*)d_in[6];
    const float* bnb   = (const float*)d_in[7];
    const float* fchw  = (const float*)d_in[8];
    const float* fchb  = (const float*)d_in[9];
    const float* fcvw  = (const float*)d_in[10];
    const float* fcvb  = (const float*)d_in[11];
    float* out = (float*)d_out;

    char* ws = (char*)d_ws;
    // layout (bytes):
    // s16    @ 0         13,107,200  (fp16 spikes [T*B][L][D])
    // smean  @ 13107200   6,553,600
    // y      @ 19660800  41,779,200
    // whl    @ 61440000  10,240,000  (fp16 hi/lo weights [i][dk][16][128])
    // statm  @ 71680000       1,600
    // stats_ @ 71681600       1,600
    // ps     @ 71683200     409,600   -> total 72,092,800
    _Float16* s16   = (_Float16*)(ws);
    float* smean    = (float*)(ws + 13107200LL);
    float* y        = (float*)(ws + 19660800LL);
    _Float16* whl   = (_Float16*)(ws + 61440000LL);
    float* statm    = (float*)(ws + 71680000LL);
    float* stats_   = (float*)(ws + 71681600LL);
    float* ps       = (float*)(ws + 71683200LL);

    k0_wsplit<<<dim3(L_, L_), 256, 0, stream>>>(convh, whl);
    k1_embed_ln_lif<<<B_ * L_, 128, 0, stream>>>(item, tab, lng, lnb, s16, smean);
    k2_convh_mfma<<<dim3(TB_ / 4, L_), 256, 0, stream>>>(s16, whl, y);
    k3_stats<<<400, 256, 0, stream>>>(y, bng, statm, stats_);
    k4_bn_lif_pool<<<dim3(B_, L_), 512, 0, stream>>>(y, statm, stats_, bnb, ps);
    k5_final<<<B_, 128, 0, stream>>>(smean, ps, convv, fchw, fchb, fcvw, fcvb, out);
}

// Round 4
// 336.192 us; speedup vs baseline: 15.5798x; 1.4437x over previous
//
#include <hip/hip_runtime.h>

#define B_ 256
#define L_ 50
#define D_ 128
#define T_ 4
#define NH 8
#define NV 4
#define TB_ (T_*B_)
#define EPSF 1e-5f

typedef _Float16 h8 __attribute__((ext_vector_type(8)));
typedef float f4 __attribute__((ext_vector_type(4)));

typedef __attribute__((address_space(1))) const unsigned int gas_u32;
typedef __attribute__((address_space(3))) unsigned int las_u32;
#define GLOAD_LDS16(gp, lp) __builtin_amdgcn_global_load_lds((gas_u32*)(gp), (las_u32*)(lp), 16, 0, 0)

__device__ __forceinline__ float waveSum(float v) {
    #pragma unroll
    for (int o = 32; o > 0; o >>= 1) v += __shfl_down(v, o, 64);
    return v;
}

// element offset of scale i inside y buffer: 1024*8*sum_{i'<i}(50-i')
__device__ __forceinline__ size_t yoff(int i) {
    return (size_t)8192 * (size_t)(50 * i - (i * (i - 1)) / 2);
}

// K0: split conv_h_w fp32 -> fp16 (hi | lo*1024), [i][dk][c=16][d] with
// 16B-granule pre-swizzle (granule gd stored at gd^ (c&15)); zero-pad dk>i, i>=50.
__global__ __launch_bounds__(256) void k0_wsplit(
        const float* __restrict__ w, _Float16* __restrict__ whl) {
    int dk = blockIdx.x, i = blockIdx.y;
    int t = threadIdx.x;
    int c = t >> 4, gd = t & 15;
    int h = c & 7;
    bool live = (i < 50) && (dk <= i);
    const float* src = w + (((size_t)i * NH + h) * L_ + dk) * D_ + gd * 8;
    h8 o;
    #pragma unroll
    for (int e = 0; e < 8; ++e) {
        float wv = live ? src[e] : 0.f;
        _Float16 hi = (_Float16)wv;
        o[e] = (c < 8) ? hi : (_Float16)((wv - (float)hi) * 1024.f);
    }
    *(h8*)(whl + (((size_t)i * 50 + dk) * 16 + c) * 128 + ((gd ^ c) & 15) * 8) = o;
}

// K1: embedding + LayerNorm + LIF(T=4) -> s16 [T*B][L][D] fp16 PRE-SWIZZLED, smean fp32
__global__ __launch_bounds__(128) void k1_embed_ln_lif(
        const int* __restrict__ item, const float* __restrict__ tab,
        const float* __restrict__ g, const float* __restrict__ be,
        _Float16* __restrict__ s16, float* __restrict__ smean) {
    int bid = blockIdx.x;
    int b = bid / L_, l = bid % L_;
    int d = threadIdx.x;
    int wid = d >> 6, lane = d & 63;
    __shared__ float red[2];
    int it = item[b * L_ + l];
    float e = tab[(size_t)it * D_ + d];
    float sm_ = waveSum(e);
    if (lane == 0) red[wid] = sm_;
    __syncthreads();
    float mu = (red[0] + red[1]) * (1.f / 128.f);
    __syncthreads();
    float df = e - mu;
    float s2 = waveSum(df * df);
    if (lane == 0) red[wid] = s2;
    __syncthreads();
    float var = (red[0] + red[1]) * (1.f / 128.f);
    float x = df / sqrtf(var + EPSF) * g[d] + be[d];
    float v = 0.f, acc = 0.f;
    int pos = (((d >> 3) ^ l) & 15) * 8 + (d & 7);   // pre-swizzled slot
    #pragma unroll
    for (int t = 0; t < T_; ++t) {
        v += (x - v) * 0.5f;
        float sp = (v >= 1.f) ? 1.f : 0.f;
        v *= (1.f - sp);
        s16[((size_t)(t * B_ + b) * L_ + l) * D_ + pos] = (_Float16)sp;
        acc += sp;
    }
    smean[((size_t)b * L_ + l) * D_ + d] = acc * 0.25f;
}

// ---- K2a: scale-group conv (groups of 4, Mt>=2). block=(tbq, group); wave=tb.
// LDS: A 4tb x 50 x 256B (linear, pre-swizzled) = 51200; B ring 6 x 16KB @51200.
template<int MTG>
__global__ __launch_bounds__(256, 1) void k2a(
        const _Float16* __restrict__ s16, const _Float16* __restrict__ whl,
        float* __restrict__ y, int gbase) {
    extern __shared__ __align__(16) char lds[];
    char* bring = lds + 51200;
    const int tbq = blockIdx.x;
    const int grp = gbase + blockIdx.y;
    const int i0 = grp * 4;
    const int kmax = i0 + 4;
    const int tid = threadIdx.x;
    const int wave = tid >> 6, lane = tid & 63;
    const int c_ = lane & 15, g = lane >> 4;

    // stage A (linear copy; swizzle baked into s16)
    {
        const float4* src = (const float4*)(s16 + (size_t)tbq * 4 * (L_ * D_));
        float4* dst = (float4*)lds;
        for (int idx = tid; idx < 3200; idx += 256) dst[idx] = src[idx];
    }
    // B ring prologue: slots 0..4; wave w stages scale i0+w (4x1KB per slot)
    const char* bsrc = (const char*)(whl + ((size_t)(i0 + wave) * 50) * 2048);
    {
        #pragma unroll
        for (int s = 0; s < 5; ++s) {
            if (s < kmax) {
                const char* gp = bsrc + (size_t)s * 4096 + lane * 16;
                char* lp = bring + s * 16384 + wave * 4096 + lane * 16;
                #pragma unroll
                for (int q = 0; q < 4; ++q)
                    GLOAD_LDS16(gp + q * 1024, lp + q * 1024);
            }
        }
    }
    asm volatile("s_waitcnt lgkmcnt(0)" ::: "memory");
    __builtin_amdgcn_s_barrier();
    __builtin_amdgcn_sched_barrier(0);

    f4 acc[4][MTG];
    #pragma unroll
    for (int s = 0; s < 4; ++s)
        #pragma unroll
        for (int j = 0; j < MTG; ++j) { f4 z = {0.f, 0.f, 0.f, 0.f}; acc[s][j] = z; }

    const char* Abase = lds + wave * 12800;
    int boff[4];
    #pragma unroll
    for (int dc = 0; dc < 4; ++dc)
        boff[dc] = c_ * 256 + ((((dc << 2) + g) ^ c_) & 15) * 16;

    int rdpos = 0, wrpos = 81920;  // slot dk, slot dk+5
    for (int dk = 0; dk < kmax; ++dk) {
        int ahead = kmax - 1 - dk; if (ahead > 4) ahead = 4;
        if (ahead >= 4)      asm volatile("s_waitcnt vmcnt(16)" ::: "memory");
        else if (ahead == 3) asm volatile("s_waitcnt vmcnt(12)" ::: "memory");
        else if (ahead == 2) asm volatile("s_waitcnt vmcnt(8)" ::: "memory");
        else if (ahead == 1) asm volatile("s_waitcnt vmcnt(4)" ::: "memory");
        else                 asm volatile("s_waitcnt vmcnt(0)" ::: "memory");
        __builtin_amdgcn_s_barrier();
        __builtin_amdgcn_sched_barrier(0);
        if (dk + 5 < kmax) {
            const char* gp = bsrc + (size_t)(dk + 5) * 4096 + lane * 16;
            char* lp = bring + wrpos + wave * 4096 + lane * 16;
            #pragma unroll
            for (int q = 0; q < 4; ++q)
                GLOAD_LDS16(gp + q * 1024, lp + q * 1024);
        }
        const char* Bs = bring + rdpos;
        #pragma unroll
        for (int dc = 0; dc < 4; ++dc) {
            h8 b0 = *(const h8*)(Bs + boff[dc]);
            h8 b1 = *(const h8*)(Bs + 4096 + boff[dc]);
            h8 b2 = *(const h8*)(Bs + 8192 + boff[dc]);
            h8 b3 = *(const h8*)(Bs + 12288 + boff[dc]);
            #pragma unroll
            for (int jt = 0; jt < MTG; ++jt) {
                int l = jt * 16 + c_ + dk; if (l > 49) l = 49;
                h8 a = *(const h8*)(Abase + l * 256 + ((((dc << 2) + g) ^ l) & 15) * 16);
                acc[0][jt] = __builtin_amdgcn_mfma_f32_16x16x32_f16(a, b0, acc[0][jt], 0, 0, 0);
                acc[1][jt] = __builtin_amdgcn_mfma_f32_16x16x32_f16(a, b1, acc[1][jt], 0, 0, 0);
                acc[2][jt] = __builtin_amdgcn_mfma_f32_16x16x32_f16(a, b2, acc[2][jt], 0, 0, 0);
                acc[3][jt] = __builtin_amdgcn_mfma_f32_16x16x32_f16(a, b3, acc[3][jt], 0, 0, 0);
            }
        }
        rdpos += 16384; if (rdpos == 98304) rdpos = 0;
        wrpos += 16384; if (wrpos == 98304) wrpos = 0;
    }
    // epilogue: combine hi + lo/1024, masked store
    const int tb = tbq * 4 + wave;
    const bool hiLane = (c_ < 8);
    const int h = c_ & 7;
    #pragma unroll
    for (int s = 0; s < 4; ++s) {
        const int i = i0 + s;
        const int J = 50 - i;
        size_t yb = yoff(i) + ((size_t)tb * NH + h) * J;
        #pragma unroll
        for (int jt = 0; jt < MTG; ++jt) {
            #pragma unroll
            for (int r = 0; r < 4; ++r) {
                float lo = __shfl_xor(acc[s][jt][r], 8, 64);
                int j = jt * 16 + g * 4 + r;
                if (hiLane && j < J) y[yb + j] = acc[s][jt][r] + lo * (1.f / 1024.f);
            }
        }
    }
}

// ---- K2c: tail scales (Mt=1, i>=36). block = 8 tb, waves=(tq, sg): 4 tb x 2 scales.
// LDS: A 8tb x 12800 = 102400; B ring 3 x 16KB @102400.
__global__ __launch_bounds__(256, 1) void k2c(
        const _Float16* __restrict__ s16, const _Float16* __restrict__ whl,
        float* __restrict__ y) {
    extern __shared__ __align__(16) char lds[];
    char* bring = lds + 102400;
    const int tbo = blockIdx.x;
    const int i0 = 36 + blockIdx.y * 4;
    const int kmax = (i0 + 4 <= 50) ? (i0 + 4) : 50;
    const int tid = threadIdx.x;
    const int wave = tid >> 6, lane = tid & 63;
    const int tq = wave & 1, sg = wave >> 1;
    const int c_ = lane & 15, g = lane >> 4;

    {
        const float4* src = (const float4*)(s16 + (size_t)tbo * 8 * (L_ * D_));
        float4* dst = (float4*)lds;
        for (int idx = tid; idx < 6400; idx += 256) dst[idx] = src[idx];
    }
    const char* bsrc = (const char*)(whl + ((size_t)(i0 + wave) * 50) * 2048);
    {
        #pragma unroll
        for (int s = 0; s < 2; ++s) {
            const char* gp = bsrc + (size_t)s * 4096 + lane * 16;
            char* lp = bring + s * 16384 + wave * 4096 + lane * 16;
            #pragma unroll
            for (int q = 0; q < 4; ++q)
                GLOAD_LDS16(gp + q * 1024, lp + q * 1024);
        }
    }
    asm volatile("s_waitcnt lgkmcnt(0)" ::: "memory");
    __builtin_amdgcn_s_barrier();
    __builtin_amdgcn_sched_barrier(0);

    f4 acc[2][4];
    #pragma unroll
    for (int s = 0; s < 2; ++s)
        #pragma unroll
        for (int t = 0; t < 4; ++t) { f4 z = {0.f, 0.f, 0.f, 0.f}; acc[s][t] = z; }

    const char* Aq = lds + (tq * 4) * 12800;
    int boff[4];
    #pragma unroll
    for (int dc = 0; dc < 4; ++dc)
        boff[dc] = c_ * 256 + ((((dc << 2) + g) ^ c_) & 15) * 16;

    int rdpos = 0, wrpos = 32768;
    for (int dk = 0; dk < kmax; ++dk) {
        if (dk + 1 < kmax) asm volatile("s_waitcnt vmcnt(4)" ::: "memory");
        else               asm volatile("s_waitcnt vmcnt(0)" ::: "memory");
        __builtin_amdgcn_s_barrier();
        __builtin_amdgcn_sched_barrier(0);
        if (dk + 2 < kmax) {
            const char* gp = bsrc + (size_t)(dk + 2) * 4096 + lane * 16;
            char* lp = bring + wrpos + wave * 4096 + lane * 16;
            #pragma unroll
            for (int q = 0; q < 4; ++q)
                GLOAD_LDS16(gp + q * 1024, lp + q * 1024);
        }
        const char* Bs = bring + rdpos + sg * 8192;
        #pragma unroll
        for (int dc = 0; dc < 4; ++dc) {
            h8 b0 = *(const h8*)(Bs + boff[dc]);
            h8 b1 = *(const h8*)(Bs + 4096 + boff[dc]);
            int l = c_ + dk; if (l > 49) l = 49;
            int aoff = l * 256 + ((((dc << 2) + g) ^ l) & 15) * 16;
            #pragma unroll
            for (int tbL = 0; tbL < 4; ++tbL) {
                h8 a = *(const h8*)(Aq + tbL * 12800 + aoff);
                acc[0][tbL] = __builtin_amdgcn_mfma_f32_16x16x32_f16(a, b0, acc[0][tbL], 0, 0, 0);
                acc[1][tbL] = __builtin_amdgcn_mfma_f32_16x16x32_f16(a, b1, acc[1][tbL], 0, 0, 0);
            }
        }
        rdpos += 16384; if (rdpos == 49152) rdpos = 0;
        wrpos += 16384; if (wrpos == 49152) wrpos = 0;
    }
    const bool hiLane = (c_ < 8);
    const int h = c_ & 7;
    #pragma unroll
    for (int s = 0; s < 2; ++s) {
        const int i = i0 + sg * 2 + s;
        const int J = 50 - i;
        if (J <= 0) continue;
        #pragma unroll
        for (int tbL = 0; tbL < 4; ++tbL) {
            const int tb = tbo * 8 + tq * 4 + tbL;
            size_t yb = yoff(i) + ((size_t)tb * NH + h) * J;
            #pragma unroll
            for (int r = 0; r < 4; ++r) {
                float lo = __shfl_xor(acc[s][tbL][r], 8, 64);
                int j = g * 4 + r;
                if (hiLane && j < J) y[yb + j] = acc[s][tbL][r] + lo * (1.f / 1024.f);
            }
        }
    }
}

// K3: BN stats, two stage (partial over 128-tb chunks, then final)
__global__ __launch_bounds__(256) void k3_partial(
        const float* __restrict__ y, float* __restrict__ psum) {
    int ih = blockIdx.x, ck = blockIdx.y;
    int i = ih >> 3, h = ih & 7;
    int J = 50 - i;
    size_t yb = yoff(i);
    int tid = threadIdx.x;
    int grp = tid >> 5, sub = tid & 31;
    float sm = 0.f, ss = 0.f;
    for (int tb = ck * 128 + grp; tb < (ck + 1) * 128; tb += 8) {
        const float* row = y + yb + ((size_t)tb * NH + h) * J;
        for (int j = sub; j < J; j += 32) { float v = row[j]; sm += v; ss += v * v; }
    }
    __shared__ float r1[4], r2[4];
    float a = waveSum(sm), b = waveSum(ss);
    int wid = tid >> 6, lane = tid & 63;
    if (lane == 0) { r1[wid] = a; r2[wid] = b; }
    __syncthreads();
    if (tid == 0) {
        psum[((size_t)ih * 8 + ck) * 2]     = r1[0] + r1[1] + r1[2] + r1[3];
        psum[((size_t)ih * 8 + ck) * 2 + 1] = r2[0] + r2[1] + r2[2] + r2[3];
    }
}

__global__ __launch_bounds__(256) void k3_final(
        const float* __restrict__ psum, const float* __restrict__ bng,
        float* __restrict__ statm, float* __restrict__ stats_) {
    int ih = blockIdx.x * 256 + threadIdx.x;
    if (ih >= 400) return;
    float S = 0.f, Q = 0.f;
    for (int ck = 0; ck < 8; ++ck) {
        S += psum[((size_t)ih * 8 + ck) * 2];
        Q += psum[((size_t)ih * 8 + ck) * 2 + 1];
    }
    int i = ih >> 3;
    float cnt = 1024.f * (float)(50 - i);
    float m = S / cnt;
    float var = Q / cnt - m * m; if (var < 0.f) var = 0.f;
    statm[ih] = m;
    stats_[ih] = bng[ih] / sqrtf(var + EPSF);
}

// K4: BN + LIF over t + max-pool over j -> poolsum [B,400]
__global__ __launch_bounds__(512) void k4_bn_lif_pool(
        const float* __restrict__ y, const float* __restrict__ statm,
        const float* __restrict__ stats_, const float* __restrict__ bnb,
        float* __restrict__ ps) {
    int b = blockIdx.x, i = blockIdx.y, J = L_ - i;
    int h = threadIdx.x >> 6, lane = threadIdx.x & 63;
    int ih = i * NH + h;
    float m = statm[ih], sc = stats_[ih], bb = bnb[ih];
    size_t yb = yoff(i);
    bool valid = lane < J;
    float v = 0.f; int cnt = 0;
    #pragma unroll
    for (int t = 0; t < T_; ++t) {
        int tb = t * B_ + b;
        float yn;
        if (valid) {
            float raw = y[yb + ((size_t)tb * NH + h) * J + lane];
            yn = (raw - m) * sc + bb;
        } else yn = -1e30f;
        v += (yn - v) * 0.5f;
        bool sp = (v >= 1.f);
        if (sp) v = 0.f;
        if (__any(sp)) cnt++;
    }
    if (lane == 0) ps[(size_t)b * 400 + ih] = (float)cnt;
}

// K5: fused heads
__global__ __launch_bounds__(128) void k5_final(
        const float* __restrict__ smean, const float* __restrict__ ps,
        const float* __restrict__ convv, const float* __restrict__ fchw,
        const float* __restrict__ fchb, const float* __restrict__ fcvw,
        const float* __restrict__ fcvb, float* __restrict__ out) {
    __shared__ float sm_l[L_ * D_];
    __shared__ float vm[NV * D_];
    __shared__ float ps_l[400];
    int b = blockIdx.x, tid = threadIdx.x;
    for (int idx = tid; idx < L_ * D_; idx += 128) sm_l[idx] = smean[(size_t)b * (L_ * D_) + idx];
    for (int idx = tid; idx < 400; idx += 128) ps_l[idx] = ps[(size_t)b * 400 + idx];
    __syncthreads();
    int d = tid;
    #pragma unroll
    for (int c = 0; c < NV; ++c) {
        float a = 0.f;
        for (int l = 0; l < L_; ++l) a += convv[c * L_ + l] * sm_l[l * D_ + d];
        vm[c * D_ + d] = a;
    }
    __syncthreads();
    float acc = fchb[d] + fcvb[d];
    float ah = 0.f;
    for (int ih = 0; ih < 400; ++ih) ah += ps_l[ih] * fchw[d * 400 + ih];
    acc += ah * 0.25f;
    float av = 0.f;
    for (int cd = 0; cd < NV * D_; ++cd) av += vm[cd] * fcvw[d * (NV * D_) + cd];
    acc += av;
    out[(size_t)b * D_ + d] = acc;
}

extern "C" void kernel_launch(void* const* d_in, const int* in_sizes, int n_in,
                              void* d_out, int out_size, void* d_ws, size_t ws_size,
                              hipStream_t stream) {
    const int*   item  = (const int*)d_in[0];
    const float* tab   = (const float*)d_in[1];
    const float* lng   = (const float*)d_in[2];
    const float* lnb   = (const float*)d_in[3];
    const float* convv = (const float*)d_in[4];
    const float* convh = (const float*)d_in[5];
    const float* bng   = (const float*)d_in[6];
    const float* bnb   = (const float*)d_in[7];
    const float* fchw  = (const float*)d_in[8];
    const float* fchb  = (const float*)d_in[9];
    const float* fcvw  = (const float*)d_in[10];
    const float* fcvb  = (const float*)d_in[11];
    float* out = (float*)d_out;

    char* ws = (char*)d_ws;
    // layout (bytes):
    // s16    @ 0          13,107,200   fp16 spikes, pre-swizzled granules
    // smean  @ 13107200    6,553,600
    // y      @ 19660800   41,779,200
    // whl    @ 61440000   10,649,600   fp16 hi/lo weights [52][50][16][128], zero-padded
    // statm  @ 72089600        1,600
    // stats_ @ 72091200        1,600
    // ps     @ 72092800      409,600
    // psum   @ 72502400       25,600   -> total 72,528,000
    _Float16* s16  = (_Float16*)(ws);
    float* smean   = (float*)(ws + 13107200LL);
    float* y       = (float*)(ws + 19660800LL);
    _Float16* whl  = (_Float16*)(ws + 61440000LL);
    float* statm   = (float*)(ws + 72089600LL);
    float* stats_  = (float*)(ws + 72091200LL);
    float* ps      = (float*)(ws + 72092800LL);
    float* psum    = (float*)(ws + 72502400LL);

    hipFuncSetAttribute(reinterpret_cast<const void*>(&k2a<4>),
        hipFuncAttributeMaxDynamicSharedMemorySize, 149504);
    hipFuncSetAttribute(reinterpret_cast<const void*>(&k2a<3>),
        hipFuncAttributeMaxDynamicSharedMemorySize, 149504);
    hipFuncSetAttribute(reinterpret_cast<const void*>(&k2a<2>),
        hipFuncAttributeMaxDynamicSharedMemorySize, 149504);
    hipFuncSetAttribute(reinterpret_cast<const void*>(&k2c),
        hipFuncAttributeMaxDynamicSharedMemorySize, 151552);

    k0_wsplit<<<dim3(50, 52), 256, 0, stream>>>(convh, whl);
    k1_embed_ln_lif<<<B_ * L_, 128, 0, stream>>>(item, tab, lng, lnb, s16, smean);
    k2a<4><<<dim3(256, 1), 256, 149504, stream>>>(s16, whl, y, 0);   // scales 0-3
    k2a<3><<<dim3(256, 4), 256, 149504, stream>>>(s16, whl, y, 1);   // scales 4-19
    k2a<2><<<dim3(256, 4), 256, 149504, stream>>>(s16, whl, y, 5);   // scales 20-35
    k2c<<<dim3(128, 4), 256, 151552, stream>>>(s16, whl, y);         // scales 36-49
    k3_partial<<<dim3(400, 8), 256, 0, stream>>>(y, psum);
    k3_final<<<dim3(2, 1), 256, 0, stream>>>(psum, bng, statm, stats_);
    k4_bn_lif_pool<<<dim3(B_, L_), 512, 0, stream>>>(y, statm, stats_, bnb, ps);
    k5_final<<<B_, 128, 0, stream>>>(smean, ps, convv, fchw, fchb, fcvw, fcvb, out);
}

// Round 5
// 290.575 us; speedup vs baseline: 18.0257x; 1.1570x over previous
//
#include <hip/hip_runtime.h>

#define B_ 256
#define L_ 50
#define D_ 128
#define T_ 4
#define NH 8
#define NV 4
#define TB_ (T_*B_)
#define EPSF 1e-5f

typedef _Float16 h8 __attribute__((ext_vector_type(8)));
typedef float f4 __attribute__((ext_vector_type(4)));

typedef __attribute__((address_space(1))) const unsigned int gas_u32;
typedef __attribute__((address_space(3))) unsigned int las_u32;
#define GLOAD_LDS16(gp, lp) __builtin_amdgcn_global_load_lds((gas_u32*)(gp), (las_u32*)(lp), 16, 0, 0)

__device__ __forceinline__ float waveSum(float v) {
    #pragma unroll
    for (int o = 32; o > 0; o >>= 1) v += __shfl_down(v, o, 64);
    return v;
}

// element offset of scale i inside y buffer: 1024*8*sum_{i'<i}(50-i')
__device__ __forceinline__ size_t yoff(int i) {
    return (size_t)8192 * (size_t)(50 * i - (i * (i - 1)) / 2);
}

// K0: split conv_h_w fp32 -> fp16 (hi | lo*1024), [i][dk][c=16][d] with
// 16B-granule pre-swizzle (granule gd stored at gd^c); zero-pad dk>i, i>=50.
__global__ __launch_bounds__(256) void k0_wsplit(
        const float* __restrict__ w, _Float16* __restrict__ whl) {
    int dk = blockIdx.x, i = blockIdx.y;
    int t = threadIdx.x;
    int c = t >> 4, gd = t & 15;
    int h = c & 7;
    bool live = (i < 50) && (dk <= i);
    const float* src = w + (((size_t)i * NH + h) * L_ + dk) * D_ + gd * 8;
    h8 o;
    #pragma unroll
    for (int e = 0; e < 8; ++e) {
        float wv = live ? src[e] : 0.f;
        _Float16 hi = (_Float16)wv;
        o[e] = (c < 8) ? hi : (_Float16)((wv - (float)hi) * 1024.f);
    }
    *(h8*)(whl + (((size_t)i * 50 + dk) * 16 + c) * 128 + ((gd ^ c) & 15) * 8) = o;
}

// K1: embedding + LayerNorm + LIF(T=4) -> s16 [T*B][L][D] fp16 PRE-SWIZZLED, smean fp32
__global__ __launch_bounds__(128) void k1_embed_ln_lif(
        const int* __restrict__ item, const float* __restrict__ tab,
        const float* __restrict__ g, const float* __restrict__ be,
        _Float16* __restrict__ s16, float* __restrict__ smean) {
    int bid = blockIdx.x;
    int b = bid / L_, l = bid % L_;
    int d = threadIdx.x;
    int wid = d >> 6, lane = d & 63;
    __shared__ float red[2];
    int it = item[b * L_ + l];
    float e = tab[(size_t)it * D_ + d];
    float sm_ = waveSum(e);
    if (lane == 0) red[wid] = sm_;
    __syncthreads();
    float mu = (red[0] + red[1]) * (1.f / 128.f);
    __syncthreads();
    float df = e - mu;
    float s2 = waveSum(df * df);
    if (lane == 0) red[wid] = s2;
    __syncthreads();
    float var = (red[0] + red[1]) * (1.f / 128.f);
    float x = df / sqrtf(var + EPSF) * g[d] + be[d];
    float v = 0.f, acc = 0.f;
    int pos = (((d >> 3) ^ l) & 15) * 8 + (d & 7);   // pre-swizzled slot
    #pragma unroll
    for (int t = 0; t < T_; ++t) {
        v += (x - v) * 0.5f;
        float sp = (v >= 1.f) ? 1.f : 0.f;
        v *= (1.f - sp);
        s16[((size_t)(t * B_ + b) * L_ + l) * D_ + pos] = (_Float16)sp;
        acc += sp;
    }
    smean[((size_t)b * L_ + l) * D_ + d] = acc * 0.25f;
}

// ---- K2u: unified scale-group conv, groups 0-8. 512 threads = 8 waves, 8 tb/block.
// Wave = (tb-pair p, dc-half dh): M = 2tb x MTG jt (N=4 scales), K split by dc-half.
// LDS: A 8tb x 12800 = 102400 (linear, pre-swizzled); B single slot 16KB @102400 (T14 reg-staged).
template<int MTG>
__global__ __launch_bounds__(512, 2) void k2u(
        const _Float16* __restrict__ s16, const _Float16* __restrict__ whl,
        float* __restrict__ y, int gbase) {
    extern __shared__ __align__(16) char lds[];
    char* Bslot = lds + 102400;
    const int NM = 2 * MTG;
    const int tbo = blockIdx.x;              // 8 tb per block
    const int grp = gbase + blockIdx.y;
    const int i0 = grp * 4;
    const int kmax = i0 + 4;
    const int tid = threadIdx.x;
    const int wave = tid >> 6, lane = tid & 63;
    const int p = wave >> 1;                 // tb-pair 0..3
    const int dh = wave & 1;                 // dc half 0/1
    const int c_ = lane & 15, g = lane >> 4;

    // stage A (linear copy; swizzle baked into s16)
    {
        const float4* src = (const float4*)(s16 + (size_t)tbo * 8 * (L_ * D_));
        float4* dst = (float4*)lds;
        for (int idx = tid; idx < 6400; idx += 512) dst[idx] = src[idx];
    }
    // B thread slots: bytes [o0,o0+16) and [o1,o1+16) of the 16KB dk-chunk
    const char* bsrc = (const char*)whl + (size_t)i0 * 50 * 4096;
    const int o0 = tid * 16, o1 = 8192 + tid * 16;
    const int sc0 = o0 >> 12, r0 = o0 & 4095;
    const int sc1 = o1 >> 12, r1 = o1 & 4095;
    const char* g0p = bsrc + (size_t)sc0 * (50 * 4096) + r0;
    const char* g1p = bsrc + (size_t)sc1 * (50 * 4096) + r1;

    float4 n0 = *(const float4*)(g0p);
    float4 n1 = *(const float4*)(g1p);
    __syncthreads();                      // A visible
    *(float4*)(Bslot + o0) = n0;
    *(float4*)(Bslot + o1) = n1;
    __syncthreads();

    f4 acc[4][NM];
    #pragma unroll
    for (int sc = 0; sc < 4; ++sc)
        #pragma unroll
        for (int m = 0; m < NM; ++m) { f4 z = {0.f, 0.f, 0.f, 0.f}; acc[sc][m] = z; }

    for (int dk = 0; dk < kmax; ++dk) {
        const bool more = (dk + 1 < kmax);
        float4 m0, m1;
        if (more) {
            m0 = *(const float4*)(g0p + (size_t)(dk + 1) * 4096);
            m1 = *(const float4*)(g1p + (size_t)(dk + 1) * 4096);
        }
        __builtin_amdgcn_sched_barrier(0);   // keep loads issued before consume
        #pragma unroll
        for (int dci = 0; dci < 2; ++dci) {
            const int dc = dh * 2 + dci;
            h8 bf[4];
            #pragma unroll
            for (int sc = 0; sc < 4; ++sc)
                bf[sc] = *(const h8*)(Bslot + sc * 4096 + c_ * 256 +
                                      ((((dc << 2) + g) ^ c_) & 15) * 16);
            #pragma unroll
            for (int m = 0; m < NM; ++m) {
                const int tbL = p * 2 + (m >= MTG ? 1 : 0);
                const int jt = (m >= MTG) ? m - MTG : m;
                int l = jt * 16 + c_ + dk; if (l > 49) l = 49;
                h8 a = *(const h8*)(lds + tbL * 12800 + l * 256 +
                                    ((((dc << 2) + g) ^ l) & 15) * 16);
                #pragma unroll
                for (int sc = 0; sc < 4; ++sc)
                    acc[sc][m] = __builtin_amdgcn_mfma_f32_16x16x32_f16(a, bf[sc], acc[sc][m], 0, 0, 0);
            }
        }
        __syncthreads();
        if (more) {
            *(float4*)(Bslot + o0) = m0;
            *(float4*)(Bslot + o1) = m1;
        }
        __syncthreads();
    }

    // merge dc-halves: dh=1 writes, dh=0 adds. Padded stride vs bank aliasing.
    const int STR = 2 * NM * 4 + 4;          // floats
    float* mbuf = (float*)lds;               // reuse A region
    #pragma unroll
    for (int half = 0; half < 2; ++half) {
        __syncthreads();
        if (dh == 1) {
            float* wp = mbuf + (size_t)(p * 64 + lane) * STR;
            #pragma unroll
            for (int sc = 0; sc < 2; ++sc)
                #pragma unroll
                for (int m = 0; m < NM; ++m)
                    *(f4*)(wp + (sc * NM + m) * 4) = acc[2 * half + sc][m];
        }
        __syncthreads();
        if (dh == 0) {
            const float* rp = mbuf + (size_t)(p * 64 + lane) * STR;
            #pragma unroll
            for (int sc = 0; sc < 2; ++sc)
                #pragma unroll
                for (int m = 0; m < NM; ++m)
                    acc[2 * half + sc][m] += *(const f4*)(rp + (sc * NM + m) * 4);
        }
    }

    if (dh == 0) {
        const bool hiLane = (c_ < 8);
        const int h = c_ & 7;
        #pragma unroll
        for (int sc = 0; sc < 4; ++sc) {
            const int i = i0 + sc;
            const int J = 50 - i;
            #pragma unroll
            for (int m = 0; m < NM; ++m) {
                const int tbL = p * 2 + (m >= MTG ? 1 : 0);
                const int jt = (m >= MTG) ? m - MTG : m;
                const int tb = tbo * 8 + tbL;
                size_t yb = yoff(i) + ((size_t)tb * NH + h) * J;
                #pragma unroll
                for (int r = 0; r < 4; ++r) {
                    float lo = __shfl_xor(acc[sc][m][r], 8, 64);
                    int j = jt * 16 + g * 4 + r;
                    if (hiLane && j < J) y[yb + j] = acc[sc][m][r] + lo * (1.f / 1024.f);
                }
            }
        }
    }
}

// ---- K2c: tail scales (Mt=1, i>=36). block = 8 tb, waves=(tq, sg): 4 tb x 2 scales.
// LDS: A 8tb x 12800 = 102400; B ring 3 x 16KB @102400.
__global__ __launch_bounds__(256, 1) void k2c(
        const _Float16* __restrict__ s16, const _Float16* __restrict__ whl,
        float* __restrict__ y) {
    extern __shared__ __align__(16) char lds[];
    char* bring = lds + 102400;
    const int tbo = blockIdx.x;
    const int i0 = 36 + blockIdx.y * 4;
    const int kmax = (i0 + 4 <= 50) ? (i0 + 4) : 50;
    const int tid = threadIdx.x;
    const int wave = tid >> 6, lane = tid & 63;
    const int tq = wave & 1, sg = wave >> 1;
    const int c_ = lane & 15, g = lane >> 4;

    {
        const float4* src = (const float4*)(s16 + (size_t)tbo * 8 * (L_ * D_));
        float4* dst = (float4*)lds;
        for (int idx = tid; idx < 6400; idx += 256) dst[idx] = src[idx];
    }
    const char* bsrc = (const char*)(whl + ((size_t)(i0 + wave) * 50) * 2048);
    {
        #pragma unroll
        for (int s = 0; s < 2; ++s) {
            const char* gp = bsrc + (size_t)s * 4096 + lane * 16;
            char* lp = bring + s * 16384 + wave * 4096 + lane * 16;
            #pragma unroll
            for (int q = 0; q < 4; ++q)
                GLOAD_LDS16(gp + q * 1024, lp + q * 1024);
        }
    }
    asm volatile("s_waitcnt lgkmcnt(0)" ::: "memory");
    __builtin_amdgcn_s_barrier();
    __builtin_amdgcn_sched_barrier(0);

    f4 acc[2][4];
    #pragma unroll
    for (int s = 0; s < 2; ++s)
        #pragma unroll
        for (int t = 0; t < 4; ++t) { f4 z = {0.f, 0.f, 0.f, 0.f}; acc[s][t] = z; }

    const char* Aq = lds + (tq * 4) * 12800;
    int boff[4];
    #pragma unroll
    for (int dc = 0; dc < 4; ++dc)
        boff[dc] = c_ * 256 + ((((dc << 2) + g) ^ c_) & 15) * 16;

    int rdpos = 0, wrpos = 32768;
    for (int dk = 0; dk < kmax; ++dk) {
        if (dk + 1 < kmax) asm volatile("s_waitcnt vmcnt(4)" ::: "memory");
        else               asm volatile("s_waitcnt vmcnt(0)" ::: "memory");
        __builtin_amdgcn_s_barrier();
        __builtin_amdgcn_sched_barrier(0);
        if (dk + 2 < kmax) {
            const char* gp = bsrc + (size_t)(dk + 2) * 4096 + lane * 16;
            char* lp = bring + wrpos + wave * 4096 + lane * 16;
            #pragma unroll
            for (int q = 0; q < 4; ++q)
                GLOAD_LDS16(gp + q * 1024, lp + q * 1024);
        }
        const char* Bs = bring + rdpos + sg * 8192;
        #pragma unroll
        for (int dc = 0; dc < 4; ++dc) {
            h8 b0 = *(const h8*)(Bs + boff[dc]);
            h8 b1 = *(const h8*)(Bs + 4096 + boff[dc]);
            int l = c_ + dk; if (l > 49) l = 49;
            int aoff = l * 256 + ((((dc << 2) + g) ^ l) & 15) * 16;
            #pragma unroll
            for (int tbL = 0; tbL < 4; ++tbL) {
                h8 a = *(const h8*)(Aq + tbL * 12800 + aoff);
                acc[0][tbL] = __builtin_amdgcn_mfma_f32_16x16x32_f16(a, b0, acc[0][tbL], 0, 0, 0);
                acc[1][tbL] = __builtin_amdgcn_mfma_f32_16x16x32_f16(a, b1, acc[1][tbL], 0, 0, 0);
            }
        }
        rdpos += 16384; if (rdpos == 49152) rdpos = 0;
        wrpos += 16384; if (wrpos == 49152) wrpos = 0;
    }
    const bool hiLane = (c_ < 8);
    const int h = c_ & 7;
    #pragma unroll
    for (int s = 0; s < 2; ++s) {
        const int i = i0 + sg * 2 + s;
        const int J = 50 - i;
        if (J <= 0) continue;
        #pragma unroll
        for (int tbL = 0; tbL < 4; ++tbL) {
            const int tb = tbo * 8 + tq * 4 + tbL;
            size_t yb = yoff(i) + ((size_t)tb * NH + h) * J;
            #pragma unroll
            for (int r = 0; r < 4; ++r) {
                float lo = __shfl_xor(acc[s][tbL][r], 8, 64);
                int j = g * 4 + r;
                if (hiLane && j < J) y[yb + j] = acc[s][tbL][r] + lo * (1.f / 1024.f);
            }
        }
    }
}

// K3: BN stats, two stage (partial over 128-tb chunks, then final)
__global__ __launch_bounds__(256) void k3_partial(
        const float* __restrict__ y, float* __restrict__ psum) {
    int ih = blockIdx.x, ck = blockIdx.y;
    int i = ih >> 3, h = ih & 7;
    int J = 50 - i;
    size_t yb = yoff(i);
    int tid = threadIdx.x;
    int grp = tid >> 5, sub = tid & 31;
    float sm = 0.f, ss = 0.f;
    for (int tb = ck * 128 + grp; tb < (ck + 1) * 128; tb += 8) {
        const float* row = y + yb + ((size_t)tb * NH + h) * J;
        for (int j = sub; j < J; j += 32) { float v = row[j]; sm += v; ss += v * v; }
    }
    __shared__ float r1[4], r2[4];
    float a = waveSum(sm), b = waveSum(ss);
    int wid = tid >> 6, lane = tid & 63;
    if (lane == 0) { r1[wid] = a; r2[wid] = b; }
    __syncthreads();
    if (tid == 0) {
        psum[((size_t)ih * 8 + ck) * 2]     = r1[0] + r1[1] + r1[2] + r1[3];
        psum[((size_t)ih * 8 + ck) * 2 + 1] = r2[0] + r2[1] + r2[2] + r2[3];
    }
}

__global__ __launch_bounds__(256) void k3_final(
        const float* __restrict__ psum, const float* __restrict__ bng,
        float* __restrict__ statm, float* __restrict__ stats_) {
    int ih = blockIdx.x * 256 + threadIdx.x;
    if (ih >= 400) return;
    float S = 0.f, Q = 0.f;
    for (int ck = 0; ck < 8; ++ck) {
        S += psum[((size_t)ih * 8 + ck) * 2];
        Q += psum[((size_t)ih * 8 + ck) * 2 + 1];
    }
    int i = ih >> 3;
    float cnt = 1024.f * (float)(50 - i);
    float m = S / cnt;
    float var = Q / cnt - m * m; if (var < 0.f) var = 0.f;
    statm[ih] = m;
    stats_[ih] = bng[ih] / sqrtf(var + EPSF);
}

// K4: BN + LIF over t + max-pool over j -> poolsum [B,400]
__global__ __launch_bounds__(512) void k4_bn_lif_pool(
        const float* __restrict__ y, const float* __restrict__ statm,
        const float* __restrict__ stats_, const float* __restrict__ bnb,
        float* __restrict__ ps) {
    int b = blockIdx.x, i = blockIdx.y, J = L_ - i;
    int h = threadIdx.x >> 6, lane = threadIdx.x & 63;
    int ih = i * NH + h;
    float m = statm[ih], sc = stats_[ih], bb = bnb[ih];
    size_t yb = yoff(i);
    bool valid = lane < J;
    float v = 0.f; int cnt = 0;
    #pragma unroll
    for (int t = 0; t < T_; ++t) {
        int tb = t * B_ + b;
        float yn;
        if (valid) {
            float raw = y[yb + ((size_t)tb * NH + h) * J + lane];
            yn = (raw - m) * sc + bb;
        } else yn = -1e30f;
        v += (yn - v) * 0.5f;
        bool sp = (v >= 1.f);
        if (sp) v = 0.f;
        if (__any(sp)) cnt++;
    }
    if (lane == 0) ps[(size_t)b * 400 + ih] = (float)cnt;
}

// K5: fused heads
__global__ __launch_bounds__(128) void k5_final(
        const float* __restrict__ smean, const float* __restrict__ ps,
        const float* __restrict__ convv, const float* __restrict__ fchw,
        const float* __restrict__ fchb, const float* __restrict__ fcvw,
        const float* __restrict__ fcvb, float* __restrict__ out) {
    __shared__ float sm_l[L_ * D_];
    __shared__ float vm[NV * D_];
    __shared__ float ps_l[400];
    int b = blockIdx.x, tid = threadIdx.x;
    for (int idx = tid; idx < L_ * D_; idx += 128) sm_l[idx] = smean[(size_t)b * (L_ * D_) + idx];
    for (int idx = tid; idx < 400; idx += 128) ps_l[idx] = ps[(size_t)b * 400 + idx];
    __syncthreads();
    int d = tid;
    #pragma unroll
    for (int c = 0; c < NV; ++c) {
        float a = 0.f;
        for (int l = 0; l < L_; ++l) a += convv[c * L_ + l] * sm_l[l * D_ + d];
        vm[c * D_ + d] = a;
    }
    __syncthreads();
    float acc = fchb[d] + fcvb[d];
    float ah = 0.f;
    for (int ih = 0; ih < 400; ++ih) ah += ps_l[ih] * fchw[d * 400 + ih];
    acc += ah * 0.25f;
    float av = 0.f;
    for (int cd = 0; cd < NV * D_; ++cd) av += vm[cd] * fcvw[d * (NV * D_) + cd];
    acc += av;
    out[(size_t)b * D_ + d] = acc;
}

extern "C" void kernel_launch(void* const* d_in, const int* in_sizes, int n_in,
                              void* d_out, int out_size, void* d_ws, size_t ws_size,
                              hipStream_t stream) {
    const int*   item  = (const int*)d_in[0];
    const float* tab   = (const float*)d_in[1];
    const float* lng   = (const float*)d_in[2];
    const float* lnb   = (const float*)d_in[3];
    const float* convv = (const float*)d_in[4];
    const float* convh = (const float*)d_in[5];
    const float* bng   = (const float*)d_in[6];
    const float* bnb   = (const float*)d_in[7];
    const float* fchw  = (const float*)d_in[8];
    const float* fchb  = (const float*)d_in[9];
    const float* fcvw  = (const float*)d_in[10];
    const float* fcvb  = (const float*)d_in[11];
    float* out = (float*)d_out;

    char* ws = (char*)d_ws;
    // layout (bytes):
    // s16    @ 0          13,107,200   fp16 spikes, pre-swizzled granules
    // smean  @ 13107200    6,553,600
    // y      @ 19660800   41,779,200
    // whl    @ 61440000   10,649,600   fp16 hi/lo weights [52][50][16][128], zero-padded
    // statm  @ 72089600        1,600
    // stats_ @ 72091200        1,600
    // ps     @ 72092800      409,600
    // psum   @ 72502400       25,600   -> total 72,528,000
    _Float16* s16  = (_Float16*)(ws);
    float* smean   = (float*)(ws + 13107200LL);
    float* y       = (float*)(ws + 19660800LL);
    _Float16* whl  = (_Float16*)(ws + 61440000LL);
    float* statm   = (float*)(ws + 72089600LL);
    float* stats_  = (float*)(ws + 72091200LL);
    float* ps      = (float*)(ws + 72092800LL);
    float* psum    = (float*)(ws + 72502400LL);

    hipFuncSetAttribute(reinterpret_cast<const void*>(&k2u<4>),
        hipFuncAttributeMaxDynamicSharedMemorySize, 118784);
    hipFuncSetAttribute(reinterpret_cast<const void*>(&k2u<3>),
        hipFuncAttributeMaxDynamicSharedMemorySize, 118784);
    hipFuncSetAttribute(reinterpret_cast<const void*>(&k2u<2>),
        hipFuncAttributeMaxDynamicSharedMemorySize, 118784);
    hipFuncSetAttribute(reinterpret_cast<const void*>(&k2c),
        hipFuncAttributeMaxDynamicSharedMemorySize, 151552);

    k0_wsplit<<<dim3(50, 52), 256, 0, stream>>>(convh, whl);
    k1_embed_ln_lif<<<B_ * L_, 128, 0, stream>>>(item, tab, lng, lnb, s16, smean);
    k2u<4><<<dim3(128, 1), 512, 118784, stream>>>(s16, whl, y, 0);   // scales 0-3
    k2u<3><<<dim3(128, 4), 512, 118784, stream>>>(s16, whl, y, 1);   // scales 4-19
    k2u<2><<<dim3(128, 4), 512, 118784, stream>>>(s16, whl, y, 5);   // scales 20-35
    k2c<<<dim3(128, 4), 256, 151552, stream>>>(s16, whl, y);         // scales 36-49
    k3_partial<<<dim3(400, 8), 256, 0, stream>>>(y, psum);
    k3_final<<<dim3(2, 1), 256, 0, stream>>>(psum, bng, statm, stats_);
    k4_bn_lif_pool<<<dim3(B_, L_), 512, 0, stream>>>(y, statm, stats_, bnb, ps);
    k5_final<<<B_, 128, 0, stream>>>(smean, ps, convv, fchw, fchb, fcvw, fcvb, out);
}

// Round 6
// 281.723 us; speedup vs baseline: 18.5921x; 1.0314x over previous
//
#include <hip/hip_runtime.h>

#define B_ 256
#define L_ 50
#define D_ 128
#define T_ 4
#define NH 8
#define NV 4
#define TB_ (T_*B_)
#define EPSF 1e-5f

typedef _Float16 h8 __attribute__((ext_vector_type(8)));
typedef float f4 __attribute__((ext_vector_type(4)));

typedef __attribute__((address_space(1))) const unsigned int gas_u32;
typedef __attribute__((address_space(3))) unsigned int las_u32;
#define GLOAD_LDS16(gp, lp) __builtin_amdgcn_global_load_lds((gas_u32*)(gp), (las_u32*)(lp), 16, 0, 0)

__device__ __forceinline__ float waveSum(float v) {
    #pragma unroll
    for (int o = 32; o > 0; o >>= 1) v += __shfl_down(v, o, 64);
    return v;
}

// element offset of scale i inside y buffer: 1024*8*sum_{i'<i}(50-i')
__device__ __forceinline__ size_t yoff(int i) {
    return (size_t)8192 * (size_t)(50 * i - (i * (i - 1)) / 2);
}

// K0: split conv_h_w fp32 -> fp16 (hi | lo*1024), [i][dk][c=16][d] with
// 16B-granule pre-swizzle (granule gd stored at gd^c); zero-pad dk>i, i>=50.
__global__ __launch_bounds__(256) void k0_wsplit(
        const float* __restrict__ w, _Float16* __restrict__ whl) {
    int dk = blockIdx.x, i = blockIdx.y;
    int t = threadIdx.x;
    int c = t >> 4, gd = t & 15;
    int h = c & 7;
    bool live = (i < 50) && (dk <= i);
    const float* src = w + (((size_t)i * NH + h) * L_ + dk) * D_ + gd * 8;
    h8 o;
    #pragma unroll
    for (int e = 0; e < 8; ++e) {
        float wv = live ? src[e] : 0.f;
        _Float16 hi = (_Float16)wv;
        o[e] = (c < 8) ? hi : (_Float16)((wv - (float)hi) * 1024.f);
    }
    *(h8*)(whl + (((size_t)i * 50 + dk) * 16 + c) * 128 + ((gd ^ c) & 15) * 8) = o;
}

// K1: embedding + LayerNorm + LIF(T=4) -> s16 [T*B][L][D] fp16 PRE-SWIZZLED, smean fp32
__global__ __launch_bounds__(128) void k1_embed_ln_lif(
        const int* __restrict__ item, const float* __restrict__ tab,
        const float* __restrict__ g, const float* __restrict__ be,
        _Float16* __restrict__ s16, float* __restrict__ smean) {
    int bid = blockIdx.x;
    int b = bid / L_, l = bid % L_;
    int d = threadIdx.x;
    int wid = d >> 6, lane = d & 63;
    __shared__ float red[2];
    int it = item[b * L_ + l];
    float e = tab[(size_t)it * D_ + d];
    float sm_ = waveSum(e);
    if (lane == 0) red[wid] = sm_;
    __syncthreads();
    float mu = (red[0] + red[1]) * (1.f / 128.f);
    __syncthreads();
    float df = e - mu;
    float s2 = waveSum(df * df);
    if (lane == 0) red[wid] = s2;
    __syncthreads();
    float var = (red[0] + red[1]) * (1.f / 128.f);
    float x = df / sqrtf(var + EPSF) * g[d] + be[d];
    float v = 0.f, acc = 0.f;
    int pos = (((d >> 3) ^ l) & 15) * 8 + (d & 7);   // pre-swizzled slot
    #pragma unroll
    for (int t = 0; t < T_; ++t) {
        v += (x - v) * 0.5f;
        float sp = (v >= 1.f) ? 1.f : 0.f;
        v *= (1.f - sp);
        s16[((size_t)(t * B_ + b) * L_ + l) * D_ + pos] = (_Float16)sp;
        acc += sp;
    }
    smean[((size_t)b * L_ + l) * D_ + d] = acc * 0.25f;
}

// ---- K2u: unified scale-group conv, groups 0-8. 512 threads = 8 waves, 8 tb/block.
// Wave = (tb-pair p, dc-half dh): M = 2tb x MTG jt (N=4 scales), K split by dc-half.
// LDS: A 8tb x 12800 = 102400 (linear, pre-swizzled); B single slot 16KB @102400 (T14 reg-staged).
template<int MTG>
__global__ __launch_bounds__(512, 2) void k2u(
        const _Float16* __restrict__ s16, const _Float16* __restrict__ whl,
        float* __restrict__ y, int gbase) {
    extern __shared__ __align__(16) char lds[];
    char* Bslot = lds + 102400;
    const int NM = 2 * MTG;
    const int tbo = blockIdx.x;              // 8 tb per block
    const int grp = gbase + blockIdx.y;
    const int i0 = grp * 4;
    const int kmax = i0 + 4;
    const int tid = threadIdx.x;
    const int wave = tid >> 6, lane = tid & 63;
    const int p = wave >> 1;                 // tb-pair 0..3
    const int dh = wave & 1;                 // dc half 0/1
    const int c_ = lane & 15, g = lane >> 4;

    // stage A (linear copy; swizzle baked into s16)
    {
        const float4* src = (const float4*)(s16 + (size_t)tbo * 8 * (L_ * D_));
        float4* dst = (float4*)lds;
        for (int idx = tid; idx < 6400; idx += 512) dst[idx] = src[idx];
    }
    // B thread slots: bytes [o0,o0+16) and [o1,o1+16) of the 16KB dk-chunk
    const char* bsrc = (const char*)whl + (size_t)i0 * 50 * 4096;
    const int o0 = tid * 16, o1 = 8192 + tid * 16;
    const int sc0 = o0 >> 12, r0 = o0 & 4095;
    const int sc1 = o1 >> 12, r1 = o1 & 4095;
    const char* g0p = bsrc + (size_t)sc0 * (50 * 4096) + r0;
    const char* g1p = bsrc + (size_t)sc1 * (50 * 4096) + r1;

    float4 n0 = *(const float4*)(g0p);
    float4 n1 = *(const float4*)(g1p);
    __syncthreads();                      // A visible
    *(float4*)(Bslot + o0) = n0;
    *(float4*)(Bslot + o1) = n1;
    __syncthreads();

    f4 acc[4][NM];
    #pragma unroll
    for (int sc = 0; sc < 4; ++sc)
        #pragma unroll
        for (int m = 0; m < NM; ++m) { f4 z = {0.f, 0.f, 0.f, 0.f}; acc[sc][m] = z; }

    for (int dk = 0; dk < kmax; ++dk) {
        const bool more = (dk + 1 < kmax);
        float4 m0, m1;
        if (more) {
            m0 = *(const float4*)(g0p + (size_t)(dk + 1) * 4096);
            m1 = *(const float4*)(g1p + (size_t)(dk + 1) * 4096);
        }
        __builtin_amdgcn_sched_barrier(0);   // keep loads issued before consume
        #pragma unroll
        for (int dci = 0; dci < 2; ++dci) {
            const int dc = dh * 2 + dci;
            h8 bf[4];
            #pragma unroll
            for (int sc = 0; sc < 4; ++sc)
                bf[sc] = *(const h8*)(Bslot + sc * 4096 + c_ * 256 +
                                      ((((dc << 2) + g) ^ c_) & 15) * 16);
            #pragma unroll
            for (int m = 0; m < NM; ++m) {
                const int tbL = p * 2 + (m >= MTG ? 1 : 0);
                const int jt = (m >= MTG) ? m - MTG : m;
                int l = jt * 16 + c_ + dk; if (l > 49) l = 49;
                h8 a = *(const h8*)(lds + tbL * 12800 + l * 256 +
                                    ((((dc << 2) + g) ^ l) & 15) * 16);
                #pragma unroll
                for (int sc = 0; sc < 4; ++sc)
                    acc[sc][m] = __builtin_amdgcn_mfma_f32_16x16x32_f16(a, bf[sc], acc[sc][m], 0, 0, 0);
            }
        }
        __syncthreads();
        if (more) {
            *(float4*)(Bslot + o0) = m0;
            *(float4*)(Bslot + o1) = m1;
        }
        __syncthreads();
    }

    // merge dc-halves: dh=1 writes, dh=0 adds. Padded stride vs bank aliasing.
    const int STR = 2 * NM * 4 + 4;          // floats
    float* mbuf = (float*)lds;               // reuse A region
    #pragma unroll
    for (int half = 0; half < 2; ++half) {
        __syncthreads();
        if (dh == 1) {
            float* wp = mbuf + (size_t)(p * 64 + lane) * STR;
            #pragma unroll
            for (int sc = 0; sc < 2; ++sc)
                #pragma unroll
                for (int m = 0; m < NM; ++m)
                    *(f4*)(wp + (sc * NM + m) * 4) = acc[2 * half + sc][m];
        }
        __syncthreads();
        if (dh == 0) {
            const float* rp = mbuf + (size_t)(p * 64 + lane) * STR;
            #pragma unroll
            for (int sc = 0; sc < 2; ++sc)
                #pragma unroll
                for (int m = 0; m < NM; ++m)
                    acc[2 * half + sc][m] += *(const f4*)(rp + (sc * NM + m) * 4);
        }
    }

    if (dh == 0) {
        const bool hiLane = (c_ < 8);
        const int h = c_ & 7;
        #pragma unroll
        for (int sc = 0; sc < 4; ++sc) {
            const int i = i0 + sc;
            const int J = 50 - i;
            #pragma unroll
            for (int m = 0; m < NM; ++m) {
                const int tbL = p * 2 + (m >= MTG ? 1 : 0);
                const int jt = (m >= MTG) ? m - MTG : m;
                const int tb = tbo * 8 + tbL;
                size_t yb = yoff(i) + ((size_t)tb * NH + h) * J;
                #pragma unroll
                for (int r = 0; r < 4; ++r) {
                    float lo = __shfl_xor(acc[sc][m][r], 8, 64);
                    int j = jt * 16 + g * 4 + r;
                    if (hiLane && j < J) y[yb + j] = acc[sc][m][r] + lo * (1.f / 1024.f);
                }
            }
        }
    }
}

// ---- K2t: tail scales (i>=36), optimal wave box (t=4 tb, s=4 sc, d=1 dc).
// 512 threads = 8 waves = (tb-quad tq, dc slice). 8 reads per 16 MFMAs (0.5 KB/MFMA).
// LDS: A 8tb x 12800 = 102400 (linear, pre-swizzled); B single slot 16KB @102400 (reg-staged).
// K-partials merged across the 4 dc-waves via LDS at the end.
__global__ __launch_bounds__(512, 2) void k2t(
        const _Float16* __restrict__ s16, const _Float16* __restrict__ whl,
        float* __restrict__ y) {
    extern __shared__ __align__(16) char lds[];
    char* Bslot = lds + 102400;
    const int tbo = blockIdx.x;              // 8 tb per block
    const int i0 = 36 + blockIdx.y * 4;      // 36,40,44,48 (48: scales 50,51 zero-padded)
    const int kmax = (i0 + 4 <= 50) ? (i0 + 4) : 50;
    const int tid = threadIdx.x;
    const int wave = tid >> 6, lane = tid & 63;
    const int tq = wave >> 2;                // tb-quad 0/1
    const int dc = wave & 3;                 // dc slice 0..3
    const int c_ = lane & 15, g = lane >> 4;

    // stage A
    {
        const float4* src = (const float4*)(s16 + (size_t)tbo * 8 * (L_ * D_));
        float4* dst = (float4*)lds;
        for (int idx = tid; idx < 6400; idx += 512) dst[idx] = src[idx];
    }
    // B: reg-staged double buffer (one 16KB slot = 4 scales x 4KB)
    const char* bsrc = (const char*)whl + (size_t)i0 * 50 * 4096;
    const int o0 = tid * 16, o1 = 8192 + tid * 16;
    const char* g0p = bsrc + (size_t)(o0 >> 12) * (50 * 4096) + (o0 & 4095);
    const char* g1p = bsrc + (size_t)(o1 >> 12) * (50 * 4096) + (o1 & 4095);
    float4 n0 = *(const float4*)(g0p);
    float4 n1 = *(const float4*)(g1p);
    __syncthreads();
    *(float4*)(Bslot + o0) = n0;
    *(float4*)(Bslot + o1) = n1;
    __syncthreads();

    f4 acc[4][4];                            // [sc][tt]
    #pragma unroll
    for (int sc = 0; sc < 4; ++sc)
        #pragma unroll
        for (int tt = 0; tt < 4; ++tt) { f4 z = {0.f, 0.f, 0.f, 0.f}; acc[sc][tt] = z; }

    const int boffc = c_ * 256 + ((((dc << 2) + g) ^ c_) & 15) * 16;
    for (int dk = 0; dk < kmax; ++dk) {
        const bool more = (dk + 1 < kmax);
        float4 m0, m1;
        if (more) {
            m0 = *(const float4*)(g0p + (size_t)(dk + 1) * 4096);
            m1 = *(const float4*)(g1p + (size_t)(dk + 1) * 4096);
        }
        __builtin_amdgcn_sched_barrier(0);
        h8 bf[4];
        #pragma unroll
        for (int sc = 0; sc < 4; ++sc)
            bf[sc] = *(const h8*)(Bslot + sc * 4096 + boffc);
        int l = c_ + dk; if (l > 49) l = 49;  // OOB rows produce discarded j>=J values
        const int aoff = l * 256 + ((((dc << 2) + g) ^ l) & 15) * 16;
        #pragma unroll
        for (int tt = 0; tt < 4; ++tt) {
            h8 a = *(const h8*)(lds + (tq * 4 + tt) * 12800 + aoff);
            #pragma unroll
            for (int sc = 0; sc < 4; ++sc)
                acc[sc][tt] = __builtin_amdgcn_mfma_f32_16x16x32_f16(a, bf[sc], acc[sc][tt], 0, 0, 0);
        }
        __syncthreads();
        if (more) {
            *(float4*)(Bslot + o0) = m0;
            *(float4*)(Bslot + o1) = m1;
        }
        __syncthreads();
    }

    // merge K-partials across dc=1..3 into dc=0 (LDS reuse of A region).
    // layout: f4 mbuf[row][lane], row = ((dc-1)*2+tq)*16 + sc*4+tt  (96x64x16B = 96KB)
    f4* mbuf = (f4*)lds;
    if (dc != 0) {
        f4* wp = mbuf + (size_t)(((dc - 1) * 2 + tq) * 16) * 64 + lane;
        #pragma unroll
        for (int sc = 0; sc < 4; ++sc)
            #pragma unroll
            for (int tt = 0; tt < 4; ++tt)
                wp[(sc * 4 + tt) * 64] = acc[sc][tt];
    }
    __syncthreads();
    if (dc == 0) {
        #pragma unroll
        for (int dd = 0; dd < 3; ++dd) {
            const f4* rp = mbuf + (size_t)((dd * 2 + tq) * 16) * 64 + lane;
            #pragma unroll
            for (int sc = 0; sc < 4; ++sc)
                #pragma unroll
                for (int tt = 0; tt < 4; ++tt)
                    acc[sc][tt] += rp[(sc * 4 + tt) * 64];
        }
        const bool hiLane = (c_ < 8);
        const int h = c_ & 7;
        #pragma unroll
        for (int sc = 0; sc < 4; ++sc) {
            const int i = i0 + sc;
            const int J = 50 - i;
            if (J <= 0) continue;
            #pragma unroll
            for (int tt = 0; tt < 4; ++tt) {
                const int tb = tbo * 8 + tq * 4 + tt;
                size_t yb = yoff(i) + ((size_t)tb * NH + h) * J;
                #pragma unroll
                for (int r = 0; r < 4; ++r) {
                    float lo = __shfl_xor(acc[sc][tt][r], 8, 64);
                    int j = g * 4 + r;
                    if (hiLane && j < J) y[yb + j] = acc[sc][tt][r] + lo * (1.f / 1024.f);
                }
            }
        }
    }
}

// K3: BN stats, two stage (partial over 128-tb chunks, then final)
__global__ __launch_bounds__(256) void k3_partial(
        const float* __restrict__ y, float* __restrict__ psum) {
    int ih = blockIdx.x, ck = blockIdx.y;
    int i = ih >> 3, h = ih & 7;
    int J = 50 - i;
    size_t yb = yoff(i);
    int tid = threadIdx.x;
    int grp = tid >> 5, sub = tid & 31;
    float sm = 0.f, ss = 0.f;
    for (int tb = ck * 128 + grp; tb < (ck + 1) * 128; tb += 8) {
        const float* row = y + yb + ((size_t)tb * NH + h) * J;
        for (int j = sub; j < J; j += 32) { float v = row[j]; sm += v; ss += v * v; }
    }
    __shared__ float r1[4], r2[4];
    float a = waveSum(sm), b = waveSum(ss);
    int wid = tid >> 6, lane = tid & 63;
    if (lane == 0) { r1[wid] = a; r2[wid] = b; }
    __syncthreads();
    if (tid == 0) {
        psum[((size_t)ih * 8 + ck) * 2]     = r1[0] + r1[1] + r1[2] + r1[3];
        psum[((size_t)ih * 8 + ck) * 2 + 1] = r2[0] + r2[1] + r2[2] + r2[3];
    }
}

__global__ __launch_bounds__(256) void k3_final(
        const float* __restrict__ psum, const float* __restrict__ bng,
        float* __restrict__ statm, float* __restrict__ stats_) {
    int ih = blockIdx.x * 256 + threadIdx.x;
    if (ih >= 400) return;
    float S = 0.f, Q = 0.f;
    for (int ck = 0; ck < 8; ++ck) {
        S += psum[((size_t)ih * 8 + ck) * 2];
        Q += psum[((size_t)ih * 8 + ck) * 2 + 1];
    }
    int i = ih >> 3;
    float cnt = 1024.f * (float)(50 - i);
    float m = S / cnt;
    float var = Q / cnt - m * m; if (var < 0.f) var = 0.f;
    statm[ih] = m;
    stats_[ih] = bng[ih] / sqrtf(var + EPSF);
}

// K4: BN + LIF over t + max-pool over j -> poolsum [B,400]
__global__ __launch_bounds__(512) void k4_bn_lif_pool(
        const float* __restrict__ y, const float* __restrict__ statm,
        const float* __restrict__ stats_, const float* __restrict__ bnb,
        float* __restrict__ ps) {
    int b = blockIdx.x, i = blockIdx.y, J = L_ - i;
    int h = threadIdx.x >> 6, lane = threadIdx.x & 63;
    int ih = i * NH + h;
    float m = statm[ih], sc = stats_[ih], bb = bnb[ih];
    size_t yb = yoff(i);
    bool valid = lane < J;
    float v = 0.f; int cnt = 0;
    #pragma unroll
    for (int t = 0; t < T_; ++t) {
        int tb = t * B_ + b;
        float yn;
        if (valid) {
            float raw = y[yb + ((size_t)tb * NH + h) * J + lane];
            yn = (raw - m) * sc + bb;
        } else yn = -1e30f;
        v += (yn - v) * 0.5f;
        bool sp = (v >= 1.f);
        if (sp) v = 0.f;
        if (__any(sp)) cnt++;
    }
    if (lane == 0) ps[(size_t)b * 400 + ih] = (float)cnt;
}

// K5: fused heads
__global__ __launch_bounds__(128) void k5_final(
        const float* __restrict__ smean, const float* __restrict__ ps,
        const float* __restrict__ convv, const float* __restrict__ fchw,
        const float* __restrict__ fchb, const float* __restrict__ fcvw,
        const float* __restrict__ fcvb, float* __restrict__ out) {
    __shared__ float sm_l[L_ * D_];
    __shared__ float vm[NV * D_];
    __shared__ float ps_l[400];
    int b = blockIdx.x, tid = threadIdx.x;
    for (int idx = tid; idx < L_ * D_; idx += 128) sm_l[idx] = smean[(size_t)b * (L_ * D_) + idx];
    for (int idx = tid; idx < 400; idx += 128) ps_l[idx] = ps[(size_t)b * 400 + idx];
    __syncthreads();
    int d = tid;
    #pragma unroll
    for (int c = 0; c < NV; ++c) {
        float a = 0.f;
        for (int l = 0; l < L_; ++l) a += convv[c * L_ + l] * sm_l[l * D_ + d];
        vm[c * D_ + d] = a;
    }
    __syncthreads();
    float acc = fchb[d] + fcvb[d];
    float ah = 0.f;
    for (int ih = 0; ih < 400; ++ih) ah += ps_l[ih] * fchw[d * 400 + ih];
    acc += ah * 0.25f;
    float av = 0.f;
    for (int cd = 0; cd < NV * D_; ++cd) av += vm[cd] * fcvw[d * (NV * D_) + cd];
    acc += av;
    out[(size_t)b * D_ + d] = acc;
}

extern "C" void kernel_launch(void* const* d_in, const int* in_sizes, int n_in,
                              void* d_out, int out_size, void* d_ws, size_t ws_size,
                              hipStream_t stream) {
    const int*   item  = (const int*)d_in[0];
    const float* tab   = (const float*)d_in[1];
    const float* lng   = (const float*)d_in[2];
    const float* lnb   = (const float*)d_in[3];
    const float* convv = (const float*)d_in[4];
    const float* convh = (const float*)d_in[5];
    const float* bng   = (const float*)d_in[6];
    const float* bnb   = (const float*)d_in[7];
    const float* fchw  = (const float*)d_in[8];
    const float* fchb  = (const float*)d_in[9];
    const float* fcvw  = (const float*)d_in[10];
    const float* fcvb  = (const float*)d_in[11];
    float* out = (float*)d_out;

    char* ws = (char*)d_ws;
    // layout (bytes):
    // s16    @ 0          13,107,200   fp16 spikes, pre-swizzled granules
    // smean  @ 13107200    6,553,600
    // y      @ 19660800   41,779,200
    // whl    @ 61440000   10,649,600   fp16 hi/lo weights [52][50][16][128], zero-padded
    // statm  @ 72089600        1,600
    // stats_ @ 72091200        1,600
    // ps     @ 72092800      409,600
    // psum   @ 72502400       25,600   -> total 72,528,000
    _Float16* s16  = (_Float16*)(ws);
    float* smean   = (float*)(ws + 13107200LL);
    float* y       = (float*)(ws + 19660800LL);
    _Float16* whl  = (_Float16*)(ws + 61440000LL);
    float* statm   = (float*)(ws + 72089600LL);
    float* stats_  = (float*)(ws + 72091200LL);
    float* ps      = (float*)(ws + 72092800LL);
    float* psum    = (float*)(ws + 72502400LL);

    hipFuncSetAttribute(reinterpret_cast<const void*>(&k2u<4>),
        hipFuncAttributeMaxDynamicSharedMemorySize, 118784);
    hipFuncSetAttribute(reinterpret_cast<const void*>(&k2u<3>),
        hipFuncAttributeMaxDynamicSharedMemorySize, 118784);
    hipFuncSetAttribute(reinterpret_cast<const void*>(&k2u<2>),
        hipFuncAttributeMaxDynamicSharedMemorySize, 118784);
    hipFuncSetAttribute(reinterpret_cast<const void*>(&k2t),
        hipFuncAttributeMaxDynamicSharedMemorySize, 118784);

    k0_wsplit<<<dim3(50, 52), 256, 0, stream>>>(convh, whl);
    k1_embed_ln_lif<<<B_ * L_, 128, 0, stream>>>(item, tab, lng, lnb, s16, smean);
    k2u<4><<<dim3(128, 1), 512, 118784, stream>>>(s16, whl, y, 0);   // scales 0-3
    k2u<3><<<dim3(128, 4), 512, 118784, stream>>>(s16, whl, y, 1);   // scales 4-19
    k2u<2><<<dim3(128, 4), 512, 118784, stream>>>(s16, whl, y, 5);   // scales 20-35
    k2t<<<dim3(128, 4), 512, 118784, stream>>>(s16, whl, y);         // scales 36-49
    k3_partial<<<dim3(400, 8), 256, 0, stream>>>(y, psum);
    k3_final<<<dim3(2, 1), 256, 0, stream>>>(psum, bng, statm, stats_);
    k4_bn_lif_pool<<<dim3(B_, L_), 512, 0, stream>>>(y, statm, stats_, bnb, ps);
    k5_final<<<B_, 128, 0, stream>>>(smean, ps, convv, fchw, fchb, fcvw, fcvb, out);
}